// Round 6
// baseline (1095.152 us; speedup 1.0000x reference)
//
#include <hip/hip_runtime.h>
#include <hip/hip_cooperative_groups.h>

namespace cg = cooperative_groups;

#define B_ 8
#define C_ 256
#define N_ 4096
#define R_ 64
#define STEPS_ 7
#define NCH_ 128
#define NSP_ 32
#define EPS_ 1e-6f

typedef unsigned short u16;
typedef short bf8v __attribute__((ext_vector_type(8)));
typedef float f4v __attribute__((ext_vector_type(4)));

#define MFMA(a, b, c) __builtin_amdgcn_mfma_f32_16x16x32_bf16((a), (b), (c), 0, 0, 0)

__device__ __forceinline__ u16 bf(float x) {
  union { float f; unsigned u; } v; v.f = x;
  return (u16)((v.u + 0x7FFFu + ((v.u >> 16) & 1u)) >> 16);
}
__device__ __forceinline__ float bf2f(u16 x) {
  union { unsigned u; float f; } v; v.u = (unsigned)x << 16; return v.f;
}
__device__ __forceinline__ bf8v ldf(const u16* p) { return *(const bf8v*)p; }

// ---------------- weight f32 -> bf16 ----------------
__global__ __launch_bounds__(256)
void cvt_w_kernel(const float* __restrict__ w1, const float* __restrict__ w2,
                  u16* __restrict__ w1b, u16* __restrict__ w2b) {
  const int i = blockIdx.x * 256 + threadIdx.x;
  w1b[i] = bf(w1[i]);
  w2b[i] = bf(w2[i]);
}

// ---------------- x (b,c,n) f32 -> xT (b,n,c) bf16 ----------------
__global__ __launch_bounds__(256)
void xpose_kernel(const float* __restrict__ x, u16* __restrict__ xT) {
  const int n0 = blockIdx.x * 64, c0 = blockIdx.y * 64, b = blockIdx.z;
  __shared__ float lds[64][65];
  const int t = threadIdx.x;
  const float* xb = x + (size_t)b * C_ * N_;
  const int row = t >> 4, col4 = (t & 15) * 4;
#pragma unroll
  for (int p = 0; p < 4; ++p) {
    float4 v = *(const float4*)&xb[(size_t)(c0 + row + 16 * p) * N_ + n0 + col4];
    lds[row + 16 * p][col4 + 0] = v.x; lds[row + 16 * p][col4 + 1] = v.y;
    lds[row + 16 * p][col4 + 2] = v.z; lds[row + 16 * p][col4 + 3] = v.w;
  }
  __syncthreads();
  const int r = t >> 2, cb = (t & 3) * 16;
  __align__(16) u16 tmp[16];
#pragma unroll
  for (int j = 0; j < 16; ++j) tmp[j] = bf(lds[cb + j][r]);
  u16* o = xT + (size_t)b * N_ * C_ + (size_t)(n0 + r) * C_ + c0 + cb;
  *(uint4*)o = *(uint4*)tmp;
  *(uint4*)(o + 8) = *(uint4*)(tmp + 8);
}

// ---------------- normalize bases; write f32 (d,r), bf16 (d,r), bf16 T (r,d) ----
__global__ __launch_bounds__(256)
void norm_bases_kernel(const float* __restrict__ binit, float* __restrict__ bases,
                       u16* __restrict__ bases_bf, u16* __restrict__ basesT) {
  const int b = blockIdx.x, t = threadIdx.x;
  const int rr = t & 63, dq = t >> 6;
  const float* src = binit + (size_t)b * C_ * R_;
  float* dst = bases + (size_t)b * C_ * R_;
  u16* dbf = bases_bf + (size_t)b * C_ * R_;
  u16* dT  = basesT + (size_t)b * R_ * C_;
  float vals[64];
  float s = 0.f;
#pragma unroll
  for (int i = 0; i < 64; ++i) {
    float v = src[(size_t)(dq + 4 * i) * R_ + rr];
    vals[i] = v; s = fmaf(v, v, s);
  }
  __shared__ float red[4][64];
  red[dq][rr] = s;
  __syncthreads();
  float nrm = fmaxf(sqrtf(red[0][rr] + red[1][rr] + red[2][rr] + red[3][rr]), 1e-12f);
  const float inv = 1.f / nrm;
#pragma unroll
  for (int i = 0; i < 64; ++i) {
    const int d = dq + 4 * i;
    const float v = vals[i] * inv;
    dst[(size_t)d * R_ + rr] = v;
    dbf[(size_t)d * R_ + rr] = bf(v);
    dT[(size_t)rr * C_ + d]  = bf(v);
  }
}

// ---------------- conv via MFMA: 128x128 block tile, 64x64 per wave ----------------
template<bool CONV1>
__global__ __launch_bounds__(256)
void conv_mfma_kernel(const u16* __restrict__ A, const u16* __restrict__ W,
                      const float* __restrict__ bias, u16* __restrict__ h_dn,
                      u16* __restrict__ h_nd, float* __restrict__ of32) {
  const int nb0 = blockIdx.x * 128, ob0 = blockIdx.y * 128, b = blockIdx.z;
  const int t = threadIdx.x, w = t >> 6, lane = t & 63, g = lane >> 4, c = lane & 15;
  const int n_base = nb0 + (w >> 1) * 64, o_base = ob0 + (w & 1) * 64;
  const u16* Ab = A + (size_t)b * N_ * C_;
  f4v acc[4][4] = {};
  for (int k0 = 0; k0 < C_; k0 += 32) {
    bf8v av[4], wv[4];
#pragma unroll
    for (int mi = 0; mi < 4; ++mi)
      av[mi] = ldf(Ab + (size_t)(n_base + mi * 16 + c) * C_ + k0 + g * 8);
#pragma unroll
    for (int nj = 0; nj < 4; ++nj)
      wv[nj] = ldf(W + (size_t)(o_base + nj * 16 + c) * C_ + k0 + g * 8);
#pragma unroll
    for (int mi = 0; mi < 4; ++mi)
#pragma unroll
      for (int nj = 0; nj < 4; ++nj)
        acc[mi][nj] = MFMA(av[mi], wv[nj], acc[mi][nj]);
  }
  __shared__ float lds[64][65];
  for (int p = 0; p < 4; ++p) {
    if (w == p) {
#pragma unroll
      for (int mi = 0; mi < 4; ++mi)
#pragma unroll
        for (int nj = 0; nj < 4; ++nj) {
          const float bb = CONV1 ? bias[o_base + nj * 16 + c] : 0.f;
#pragma unroll
          for (int rg = 0; rg < 4; ++rg) {
            float v = acc[mi][nj][rg];
            if (CONV1) v = fmaxf(v + bb, 0.f);
            lds[mi * 16 + g * 4 + rg][nj * 16 + c] = v;
          }
        }
    }
    __syncthreads();
    const int pn = nb0 + (p >> 1) * 64, po = ob0 + (p & 1) * 64;
    if (CONV1) {
      {
        const int n = t >> 2, ob2 = (t & 3) * 16;
        __align__(16) u16 tmp[16];
#pragma unroll
        for (int j = 0; j < 16; ++j) tmp[j] = bf(lds[n][ob2 + j]);
        u16* o = h_nd + (size_t)b * N_ * C_ + (size_t)(pn + n) * C_ + po + ob2;
        *(uint4*)o = *(uint4*)tmp; *(uint4*)(o + 8) = *(uint4*)(tmp + 8);
      }
      {
        const int oo = t >> 2, nb2 = (t & 3) * 16;
        __align__(16) u16 tmp[16];
#pragma unroll
        for (int j = 0; j < 16; ++j) tmp[j] = bf(lds[nb2 + j][oo]);
        u16* o = h_dn + (size_t)b * C_ * N_ + (size_t)(po + oo) * N_ + pn + nb2;
        *(uint4*)o = *(uint4*)tmp; *(uint4*)(o + 8) = *(uint4*)(tmp + 8);
      }
    } else {
      const int oo = t >> 2, nb2 = (t & 3) * 16;
      float* o = of32 + (size_t)b * C_ * N_ + (size_t)(po + oo) * N_ + pn + nb2;
#pragma unroll
      for (int q = 0; q < 4; ++q) {
        float4 v = make_float4(lds[nb2 + q * 4 + 0][oo], lds[nb2 + q * 4 + 1][oo],
                               lds[nb2 + q * 4 + 2][oo], lds[nb2 + q * 4 + 3][oo]);
        *(float4*)&o[q * 4] = v;
      }
    }
    __syncthreads();
  }
}

// ---------------- persistent cooperative NMF ----------------
// grid (32, 8): block = (n-chunk of 128, b). 1 block/CU.
// h chunk LDS-resident (swizzled); coef LDS-resident across all iterations.
// per iter: num+btb -> den -> coef update -> ctc/xc partials -> grid.sync
//           -> blocks x<4 do bases update -> grid.sync. it==7: compute_coef + rec.
__global__ __launch_bounds__(512, 1)
void nmf_persist_kernel(const u16* __restrict__ h_nd, const u16* __restrict__ h_dn,
                        u16* __restrict__ basesT, u16* __restrict__ bases_bf,
                        float* __restrict__ bases_f32, u16* __restrict__ rec_nd,
                        float* __restrict__ ctcp, float* __restrict__ xcp) {
  cg::grid_group gg = cg::this_grid();
  const int chunk = blockIdx.x, b = blockIdx.y;
  const int nc0 = chunk * NCH_;
  const int t = threadIdx.x, w = t >> 6, lane = t & 63, g = lane >> 4, c = lane & 15;

  __shared__ u16 h_s[128 * 256];       // 64KB, XOR-swizzled 16B chunks
  __shared__ u16 coef_s[128][72];      // 18KB, persistent
  __shared__ u16 coefT_s[64][136];     // 17KB
  __shared__ u16 btb_s[64][72];        // 9KB
  __shared__ float upd_ctc[64 * 64];   // 16KB (updater blocks)
  __shared__ float upd_b[64][65];      // 16.6KB (updater blocks)

  const u16* hb = h_nd + (size_t)b * N_ * C_;
  const u16* hd = h_dn + (size_t)b * C_ * N_;
  const u16* bT = basesT + (size_t)b * R_ * C_;

  // ---- stage h chunk: lds[r*256 + ((k ^ (r&7))*8)] = h[nc0+r][k*8..+7] ----
  {
    const int r = t >> 2;
    const u16* src = hb + (size_t)(nc0 + r) * C_;
#pragma unroll
    for (int i = 0; i < 8; ++i) {
      const int k = (t & 3) + 4 * i;
      uint4 v = *(const uint4*)&src[k * 8];
      *(uint4*)&h_s[r * 256 + ((k ^ (r & 7)) * 8)] = v;
    }
  }
  __syncthreads();

  const int nl = w * 16 + c;   // A-frag row (local)

  // ---- init: coef = softmax(h^T bases) ----
  {
    f4v num[4] = {};
    for (int k0 = 0; k0 < C_; k0 += 32) {
      bf8v a = *(const bf8v*)&h_s[nl * 256 + ((((k0 >> 3) + g) ^ (nl & 7)) * 8)];
#pragma unroll
      for (int nj = 0; nj < 4; ++nj)
        num[nj] = MFMA(a, ldf(bT + (size_t)(nj * 16 + c) * C_ + k0 + g * 8), num[nj]);
    }
#pragma unroll
    for (int rg = 0; rg < 4; ++rg) {
      float m = fmaxf(fmaxf(num[0][rg], num[1][rg]), fmaxf(num[2][rg], num[3][rg]));
#pragma unroll
      for (int off = 1; off < 16; off <<= 1) m = fmaxf(m, __shfl_xor(m, off));
      float e[4], s = 0.f;
#pragma unroll
      for (int nj = 0; nj < 4; ++nj) { e[nj] = __expf(num[nj][rg] - m); s += e[nj]; }
#pragma unroll
      for (int off = 1; off < 16; off <<= 1) s += __shfl_xor(s, off);
      const float inv = 1.f / s;
#pragma unroll
      for (int nj = 0; nj < 4; ++nj)
        coef_s[w * 16 + g * 4 + rg][nj * 16 + c] = bf(e[nj] * inv);
    }
  }
  __syncthreads();

  // ---- 7 NMF steps + compute_coef (it==7) ----
  for (int it = 0; it < 8; ++it) {
    // Phase A/B: num = h^T bases; btb on waves 0..3
    f4v num[4] = {}, bt[4] = {};
    const u16* Abt = bT + (size_t)(w * 16 + c) * C_ + g * 8;
    for (int k0 = 0; k0 < C_; k0 += 32) {
      bf8v bv[4];
#pragma unroll
      for (int nj = 0; nj < 4; ++nj)
        bv[nj] = ldf(bT + (size_t)(nj * 16 + c) * C_ + k0 + g * 8);
      bf8v a = *(const bf8v*)&h_s[nl * 256 + ((((k0 >> 3) + g) ^ (nl & 7)) * 8)];
#pragma unroll
      for (int nj = 0; nj < 4; ++nj) num[nj] = MFMA(a, bv[nj], num[nj]);
      if (w < 4) {
        bf8v a2 = ldf(Abt + k0);
#pragma unroll
        for (int nj = 0; nj < 4; ++nj) bt[nj] = MFMA(a2, bv[nj], bt[nj]);
      }
    }
    if (w < 4) {
#pragma unroll
      for (int nj = 0; nj < 4; ++nj)
#pragma unroll
        for (int rg = 0; rg < 4; ++rg)
          btb_s[w * 16 + g * 4 + rg][nj * 16 + c] = bf(bt[nj][rg]);
    }
    __syncthreads();

    // Phase C: den = coef @ btb
    f4v den[4] = {};
#pragma unroll
    for (int k0 = 0; k0 < R_; k0 += 32) {
      bf8v a = *(const bf8v*)&coef_s[nl][k0 + g * 8];
#pragma unroll
      for (int nj = 0; nj < 4; ++nj)
        den[nj] = MFMA(a, *(const bf8v*)&btb_s[nj * 16 + c][k0 + g * 8], den[nj]);
    }
    __syncthreads();   // all den reads done before in-place update

    // Phase D: multiplicative update in LDS
#pragma unroll
    for (int nj = 0; nj < 4; ++nj)
#pragma unroll
      for (int rg = 0; rg < 4; ++rg) {
        const int row = w * 16 + g * 4 + rg, r = nj * 16 + c;
        const float old = bf2f(coef_s[row][r]);
        const u16 nv = bf(old * num[nj][rg] / (den[nj][rg] + EPS_));
        coef_s[row][r] = nv;
        coefT_s[r][row] = nv;
      }
    __syncthreads();

    if (it == 7) break;

    // xc partial: all waves, d rows w*32 + mi*16
    {
      f4v xa[2][4] = {};
      for (int k0 = 0; k0 < NCH_; k0 += 32) {
        bf8v bv[4];
#pragma unroll
        for (int nj = 0; nj < 4; ++nj)
          bv[nj] = *(const bf8v*)&coefT_s[nj * 16 + c][k0 + g * 8];
#pragma unroll
        for (int mi = 0; mi < 2; ++mi) {
          bf8v a = ldf(hd + (size_t)(w * 32 + mi * 16 + c) * N_ + nc0 + k0 + g * 8);
#pragma unroll
          for (int nj = 0; nj < 4; ++nj) xa[mi][nj] = MFMA(a, bv[nj], xa[mi][nj]);
        }
      }
      float* xo = xcp + ((size_t)b * NSP_ + chunk) * (C_ * R_);
#pragma unroll
      for (int mi = 0; mi < 2; ++mi)
#pragma unroll
        for (int nj = 0; nj < 4; ++nj)
#pragma unroll
          for (int rg = 0; rg < 4; ++rg)
            xo[(size_t)(w * 32 + mi * 16 + g * 4 + rg) * R_ + nj * 16 + c] = xa[mi][nj][rg];
    }
    // ctc partial: waves 0..3
    if (w < 4) {
      f4v ca[4] = {};
      for (int k0 = 0; k0 < NCH_; k0 += 32) {
        bf8v a = *(const bf8v*)&coefT_s[w * 16 + c][k0 + g * 8];
#pragma unroll
        for (int nj = 0; nj < 4; ++nj)
          ca[nj] = MFMA(a, *(const bf8v*)&coefT_s[nj * 16 + c][k0 + g * 8], ca[nj]);
      }
      float* co = ctcp + ((size_t)b * NSP_ + chunk) * (R_ * R_);
#pragma unroll
      for (int nj = 0; nj < 4; ++nj)
#pragma unroll
        for (int rg = 0; rg < 4; ++rg)
          co[(size_t)(w * 16 + g * 4 + rg) * R_ + nj * 16 + c] = ca[nj][rg];
    }

    gg.sync();

    // bases update on blocks chunk<4 (dt = chunk)
    if (chunk < 4) {
      const int dt = chunk, d0 = dt * 64;
      float* bb = bases_f32 + (size_t)b * C_ * R_;
      {
        float4 a0 = make_float4(0, 0, 0, 0), a1 = make_float4(0, 0, 0, 0);
        for (int s = 0; s < NSP_; ++s) {
          const float* sp = ctcp + ((size_t)b * NSP_ + s) * (R_ * R_) + t * 8;
          float4 v0 = *(const float4*)sp;
          float4 v1 = *(const float4*)(sp + 4);
          a0.x += v0.x; a0.y += v0.y; a0.z += v0.z; a0.w += v0.w;
          a1.x += v1.x; a1.y += v1.y; a1.z += v1.z; a1.w += v1.w;
        }
        *(float4*)&upd_ctc[t * 8] = a0;
        *(float4*)&upd_ctc[t * 8 + 4] = a1;
      }
      {
        const int lc = t & 63, lr = t >> 6;
#pragma unroll
        for (int p = 0; p < 8; ++p)
          upd_b[lr + 8 * p][lc] = bb[(size_t)(d0 + lr + 8 * p) * R_ + lc];
      }
      __syncthreads();
#pragma unroll
      for (int half = 0; half < 2; ++half) {
        const int dd = (t >> 4) + half * 32;
        const int r0 = (t & 15) * 4;
        float4 num2 = make_float4(0, 0, 0, 0);
        for (int s = 0; s < NSP_; ++s) {
          float4 v = *(const float4*)&xcp[(((size_t)b * NSP_ + s) * C_ + d0 + dd) * R_ + r0];
          num2.x += v.x; num2.y += v.y; num2.z += v.z; num2.w += v.w;
        }
        float4 den2 = make_float4(0, 0, 0, 0);
#pragma unroll
        for (int k = 0; k < 64; ++k) {
          const float a = upd_b[dd][k];
          float4 cv = *(const float4*)&upd_ctc[k * 64 + r0];
          den2.x = fmaf(a, cv.x, den2.x); den2.y = fmaf(a, cv.y, den2.y);
          den2.z = fmaf(a, cv.z, den2.z); den2.w = fmaf(a, cv.w, den2.w);
        }
        float4 o;
        o.x = upd_b[dd][r0 + 0] * num2.x / (den2.x + EPS_);
        o.y = upd_b[dd][r0 + 1] * num2.y / (den2.y + EPS_);
        o.z = upd_b[dd][r0 + 2] * num2.z / (den2.z + EPS_);
        o.w = upd_b[dd][r0 + 3] * num2.w / (den2.w + EPS_);
        *(float4*)&bb[(size_t)(d0 + dd) * R_ + r0] = o;
        u16* obf = bases_bf + (size_t)b * C_ * R_ + (size_t)(d0 + dd) * R_ + r0;
        obf[0] = bf(o.x); obf[1] = bf(o.y); obf[2] = bf(o.z); obf[3] = bf(o.w);
        u16* oT = basesT + (size_t)b * R_ * C_ + d0 + dd;
        oT[(size_t)(r0 + 0) * C_] = bf(o.x); oT[(size_t)(r0 + 1) * C_] = bf(o.y);
        oT[(size_t)(r0 + 2) * C_] = bf(o.z); oT[(size_t)(r0 + 3) * C_] = bf(o.w);
      }
      __syncthreads();
    }

    gg.sync();
  }

  // ---- rec_nd[n,d] = sum_r coef[n,r] * bases[d,r] ----
  {
    f4v ra[8][2] = {};
    const u16* Bb = bases_bf + (size_t)b * C_ * R_;
#pragma unroll
    for (int k0 = 0; k0 < R_; k0 += 32) {
      bf8v bv[2];
#pragma unroll
      for (int nj = 0; nj < 2; ++nj)
        bv[nj] = ldf(Bb + (size_t)(w * 32 + nj * 16 + c) * R_ + k0 + g * 8);
#pragma unroll
      for (int mi = 0; mi < 8; ++mi) {
        bf8v a = *(const bf8v*)&coef_s[mi * 16 + c][k0 + g * 8];
#pragma unroll
        for (int nj = 0; nj < 2; ++nj) ra[mi][nj] = MFMA(a, bv[nj], ra[mi][nj]);
      }
    }
    u16* ro = rec_nd + (size_t)b * N_ * C_;
#pragma unroll
    for (int mi = 0; mi < 8; ++mi)
#pragma unroll
      for (int nj = 0; nj < 2; ++nj)
#pragma unroll
        for (int rg = 0; rg < 4; ++rg)
          ro[(size_t)(nc0 + mi * 16 + g * 4 + rg) * C_ + w * 32 + nj * 16 + c] =
              bf(ra[mi][nj][rg]);
  }
}

// ---------------- GroupNorm stats ----------------
__global__ __launch_bounds__(256)
void gn_stats_kernel(const float* __restrict__ o, float* __restrict__ stats) {
  const int g = blockIdx.x, b = blockIdx.y;
  const float* p = o + ((size_t)b * C_ + g * 8) * N_;
  const int t = threadIdx.x;
  float s = 0.f, s2 = 0.f;
  for (int i = t; i < 8192; i += 256) {
    float4 v = ((const float4*)p)[i];
    s += v.x + v.y + v.z + v.w;
    s2 = fmaf(v.x, v.x, s2); s2 = fmaf(v.y, v.y, s2);
    s2 = fmaf(v.z, v.z, s2); s2 = fmaf(v.w, v.w, s2);
  }
#pragma unroll
  for (int off = 32; off > 0; off >>= 1) { s += __shfl_down(s, off); s2 += __shfl_down(s2, off); }
  __shared__ float rs[4], rs2[4];
  if ((t & 63) == 0) { rs[t >> 6] = s; rs2[t >> 6] = s2; }
  __syncthreads();
  if (t == 0) {
    float S = rs[0] + rs[1] + rs[2] + rs[3];
    float S2 = rs2[0] + rs2[1] + rs2[2] + rs2[3];
    float mean = S / 32768.f;
    float var = S2 / 32768.f - mean * mean;
    stats[(b * 32 + g) * 2 + 0] = mean;
    stats[(b * 32 + g) * 2 + 1] = rsqrtf(var + 1e-5f);
  }
}

// ---------------- GN affine + residual + relu ----------------
__global__ __launch_bounds__(256)
void gn_final_kernel(const float* __restrict__ x, const float* __restrict__ gamma,
                     const float* __restrict__ beta, const float* __restrict__ stats,
                     float* __restrict__ out) {
  const size_t gid = (size_t)blockIdx.x * 256 + threadIdx.x;
  const size_t idx = gid * 4;
  const int b = (int)(idx >> 20);
  const int rem = (int)(idx & ((1u << 20) - 1));
  const int c = rem >> 12;
  const int g = c >> 3;
  const float mean = stats[(b * 32 + g) * 2 + 0];
  const float rstd = stats[(b * 32 + g) * 2 + 1];
  const float ga = gamma[c] * rstd;
  const float be = beta[c] - mean * ga;
  float4 ov = ((const float4*)out)[gid];
  float4 xv = ((const float4*)x)[gid];
  float4 r;
  r.x = fmaxf(fmaf(ov.x, ga, be) + xv.x, 0.f);
  r.y = fmaxf(fmaf(ov.y, ga, be) + xv.y, 0.f);
  r.z = fmaxf(fmaf(ov.z, ga, be) + xv.z, 0.f);
  r.w = fmaxf(fmaf(ov.w, ga, be) + xv.w, 0.f);
  ((float4*)out)[gid] = r;
}

extern "C" void kernel_launch(void* const* d_in, const int* in_sizes, int n_in,
                              void* d_out, int out_size, void* d_ws, size_t ws_size,
                              hipStream_t stream) {
  (void)in_sizes; (void)n_in; (void)out_size; (void)ws_size;
  const float* x     = (const float*)d_in[0];
  const float* w_in  = (const float*)d_in[1];
  const float* b_in  = (const float*)d_in[2];
  const float* w_out = (const float*)d_in[3];
  const float* gamma = (const float*)d_in[4];
  const float* beta  = (const float*)d_in[5];
  const float* binit = (const float*)d_in[6];
  float* out = (float*)d_out;

  float* p = (float*)d_ws;
  u16* xT = (u16*)p;        p += 4194304;   // B*N*C bf16; reused as rec_nd
  u16* rec_nd = xT;
  u16* h_nd = (u16*)p;      p += 4194304;   // B*N*C bf16
  u16* h_dn = (u16*)p;      p += 4194304;   // B*C*N bf16
  float* bases = p;         p += 131072;    // B*C*R f32
  u16* bases_bf = (u16*)p;  p += 65536;
  u16* basesT = (u16*)p;    p += 65536;
  float* ctcp = p;          p += 1048576;   // B*NSP*R*R f32
  float* xcp = p;           p += 4194304;   // B*NSP*C*R f32
  u16* w1b = (u16*)p;       p += 32768;     // C*C bf16 = 65536 u16 = 32768 floats
  u16* w2b = (u16*)p;       p += 32768;     // C*C bf16 = 65536 u16 = 32768 floats
  float* stats = p;         p += 512;

  cvt_w_kernel<<<dim3(256), 256, 0, stream>>>(w_in, w_out, w1b, w2b);
  xpose_kernel<<<dim3(64, 4, 8), 256, 0, stream>>>(x, xT);
  norm_bases_kernel<<<dim3(B_), 256, 0, stream>>>(binit, bases, bases_bf, basesT);
  conv_mfma_kernel<true><<<dim3(32, 2, 8), 256, 0, stream>>>(xT, w1b, b_in, h_dn, h_nd, nullptr);

  {
    void* args[] = {(void*)&h_nd, (void*)&h_dn, (void*)&basesT, (void*)&bases_bf,
                    (void*)&bases, (void*)&rec_nd, (void*)&ctcp, (void*)&xcp};
    hipLaunchCooperativeKernel(reinterpret_cast<void*>(nmf_persist_kernel),
                               dim3(NSP_, B_), dim3(512), args, 0, stream);
  }

  conv_mfma_kernel<false><<<dim3(32, 2, 8), 256, 0, stream>>>(rec_nd, w2b, nullptr,
                                                              nullptr, nullptr, out);
  gn_stats_kernel<<<dim3(32, 8), 256, 0, stream>>>(out, stats);
  gn_final_kernel<<<dim3((B_ * C_ * N_) / 4 / 256), 256, 0, stream>>>(x, gamma, beta, stats, out);
}

// Round 7
// 287.616 us; speedup vs baseline: 3.8077x; 3.8077x over previous
//
#include <hip/hip_runtime.h>

#define B_ 8
#define C_ 256
#define N_ 4096
#define R_ 64
#define STEPS_ 7
#define NCH_ 128
#define NSP_ 32
#define EPS_ 1e-6f

typedef unsigned short u16;
typedef short bf8v __attribute__((ext_vector_type(8)));
typedef float f4v __attribute__((ext_vector_type(4)));

#define MFMA(a, b, c) __builtin_amdgcn_mfma_f32_16x16x32_bf16((a), (b), (c), 0, 0, 0)

__device__ __forceinline__ u16 bf(float x) {
  union { float f; unsigned u; } v; v.f = x;
  return (u16)((v.u + 0x7FFFu + ((v.u >> 16) & 1u)) >> 16);
}
__device__ __forceinline__ float bf2f(u16 x) {
  union { unsigned u; float f; } v; v.u = (unsigned)x << 16; return v.f;
}
__device__ __forceinline__ bf8v ldf(const u16* p) { return *(const bf8v*)p; }

// ---------------- prep: norm_bases (blocks 0..7) + weight cvt (blocks 8..263) ----
__global__ __launch_bounds__(256)
void prep_kernel(const float* __restrict__ binit, float* __restrict__ bases,
                 u16* __restrict__ bases_bf, u16* __restrict__ basesT,
                 const float* __restrict__ w1, const float* __restrict__ w2,
                 u16* __restrict__ w1b, u16* __restrict__ w2b) {
  const int t = threadIdx.x;
  if (blockIdx.x >= 8) {
    const int i = (blockIdx.x - 8) * 256 + t;
    w1b[i] = bf(w1[i]);
    w2b[i] = bf(w2[i]);
    return;
  }
  const int b = blockIdx.x;
  const int rr = t & 63, dq = t >> 6;
  const float* src = binit + (size_t)b * C_ * R_;
  float* dst = bases + (size_t)b * C_ * R_;
  u16* dbf = bases_bf + (size_t)b * C_ * R_;
  u16* dT  = basesT + (size_t)b * R_ * C_;
  float vals[64];
  float s = 0.f;
#pragma unroll
  for (int i = 0; i < 64; ++i) {
    float v = src[(size_t)(dq + 4 * i) * R_ + rr];
    vals[i] = v; s = fmaf(v, v, s);
  }
  __shared__ float red[4][64];
  red[dq][rr] = s;
  __syncthreads();
  float nrm = fmaxf(sqrtf(red[0][rr] + red[1][rr] + red[2][rr] + red[3][rr]), 1e-12f);
  const float inv = 1.f / nrm;
#pragma unroll
  for (int i = 0; i < 64; ++i) {
    const int d = dq + 4 * i;
    const float v = vals[i] * inv;
    dst[(size_t)d * R_ + rr] = v;
    dbf[(size_t)d * R_ + rr] = bf(v);
    dT[(size_t)rr * C_ + d]  = bf(v);
  }
}

// ---------------- x (b,c,n) f32 -> xT (b,n,c) bf16 ----------------
__global__ __launch_bounds__(256)
void xpose_kernel(const float* __restrict__ x, u16* __restrict__ xT) {
  const int n0 = blockIdx.x * 64, c0 = blockIdx.y * 64, b = blockIdx.z;
  __shared__ float lds[64][65];
  const int t = threadIdx.x;
  const float* xb = x + (size_t)b * C_ * N_;
  const int row = t >> 4, col4 = (t & 15) * 4;
#pragma unroll
  for (int p = 0; p < 4; ++p) {
    float4 v = *(const float4*)&xb[(size_t)(c0 + row + 16 * p) * N_ + n0 + col4];
    lds[row + 16 * p][col4 + 0] = v.x; lds[row + 16 * p][col4 + 1] = v.y;
    lds[row + 16 * p][col4 + 2] = v.z; lds[row + 16 * p][col4 + 3] = v.w;
  }
  __syncthreads();
  const int r = t >> 2, cb = (t & 3) * 16;
  __align__(16) u16 tmp[16];
#pragma unroll
  for (int j = 0; j < 16; ++j) tmp[j] = bf(lds[cb + j][r]);
  u16* o = xT + (size_t)b * N_ * C_ + (size_t)(n0 + r) * C_ + c0 + cb;
  *(uint4*)o = *(uint4*)tmp;
  *(uint4*)(o + 8) = *(uint4*)(tmp + 8);
}

// ---------------- conv via MFMA: 128x128 block tile, 64x64 per wave ----------------
// CONV1: +bias+relu, writes h_dn/h_nd bf16.  !CONV1: writes of32 + GN partial stats.
template<bool CONV1>
__global__ __launch_bounds__(256)
void conv_mfma_kernel(const u16* __restrict__ A, const u16* __restrict__ W,
                      const float* __restrict__ bias, u16* __restrict__ h_dn,
                      u16* __restrict__ h_nd, float* __restrict__ of32,
                      float* __restrict__ pstats) {
  const int nb0 = blockIdx.x * 128, ob0 = blockIdx.y * 128, b = blockIdx.z;
  const int t = threadIdx.x, w = t >> 6, lane = t & 63, g = lane >> 4, c = lane & 15;
  const int n_base = nb0 + (w >> 1) * 64, o_base = ob0 + (w & 1) * 64;
  const u16* Ab = A + (size_t)b * N_ * C_;
  f4v acc[4][4] = {};
  for (int k0 = 0; k0 < C_; k0 += 32) {
    bf8v av[4], wv[4];
#pragma unroll
    for (int mi = 0; mi < 4; ++mi)
      av[mi] = ldf(Ab + (size_t)(n_base + mi * 16 + c) * C_ + k0 + g * 8);
#pragma unroll
    for (int nj = 0; nj < 4; ++nj)
      wv[nj] = ldf(W + (size_t)(o_base + nj * 16 + c) * C_ + k0 + g * 8);
#pragma unroll
    for (int mi = 0; mi < 4; ++mi)
#pragma unroll
      for (int nj = 0; nj < 4; ++nj)
        acc[mi][nj] = MFMA(av[mi], wv[nj], acc[mi][nj]);
  }
  __shared__ float lds[64][65];
  float sacc0 = 0.f, sacc1 = 0.f, s2acc0 = 0.f, s2acc1 = 0.f;
  for (int p = 0; p < 4; ++p) {
    if (w == p) {
#pragma unroll
      for (int mi = 0; mi < 4; ++mi)
#pragma unroll
        for (int nj = 0; nj < 4; ++nj) {
          const float bb = CONV1 ? bias[o_base + nj * 16 + c] : 0.f;
#pragma unroll
          for (int rg = 0; rg < 4; ++rg) {
            float v = acc[mi][nj][rg];
            if (CONV1) v = fmaxf(v + bb, 0.f);
            lds[mi * 16 + g * 4 + rg][nj * 16 + c] = v;
          }
        }
    }
    __syncthreads();
    const int pn = nb0 + (p >> 1) * 64, po = ob0 + (p & 1) * 64;
    if (CONV1) {
      {
        const int n = t >> 2, ob2 = (t & 3) * 16;
        __align__(16) u16 tmp[16];
#pragma unroll
        for (int j = 0; j < 16; ++j) tmp[j] = bf(lds[n][ob2 + j]);
        u16* o = h_nd + (size_t)b * N_ * C_ + (size_t)(pn + n) * C_ + po + ob2;
        *(uint4*)o = *(uint4*)tmp; *(uint4*)(o + 8) = *(uint4*)(tmp + 8);
      }
      {
        const int oo = t >> 2, nb2 = (t & 3) * 16;
        __align__(16) u16 tmp[16];
#pragma unroll
        for (int j = 0; j < 16; ++j) tmp[j] = bf(lds[nb2 + j][oo]);
        u16* o = h_dn + (size_t)b * C_ * N_ + (size_t)(po + oo) * N_ + pn + nb2;
        *(uint4*)o = *(uint4*)tmp; *(uint4*)(o + 8) = *(uint4*)(tmp + 8);
      }
    } else {
      const int oo = t >> 2, nb2 = (t & 3) * 16;
      float* o = of32 + (size_t)b * C_ * N_ + (size_t)(po + oo) * N_ + pn + nb2;
      float ls = 0.f, ls2 = 0.f;
#pragma unroll
      for (int q = 0; q < 4; ++q) {
        float4 v = make_float4(lds[nb2 + q * 4 + 0][oo], lds[nb2 + q * 4 + 1][oo],
                               lds[nb2 + q * 4 + 2][oo], lds[nb2 + q * 4 + 3][oo]);
        *(float4*)&o[q * 4] = v;
        ls += v.x + v.y + v.z + v.w;
        ls2 = fmaf(v.x, v.x, ls2); ls2 = fmaf(v.y, v.y, ls2);
        ls2 = fmaf(v.z, v.z, ls2); ls2 = fmaf(v.w, v.w, ls2);
      }
      if ((p & 1) == 0) { sacc0 += ls; s2acc0 += ls2; }
      else              { sacc1 += ls; s2acc1 += ls2; }
    }
    __syncthreads();
  }
  if (!CONV1) {
    const int oo = t >> 2, q4 = t & 3;
    lds[oo][q4] = sacc0;      lds[oo][4 + q4] = s2acc0;
    lds[oo][8 + q4] = sacc1;  lds[oo][12 + q4] = s2acc1;
    __syncthreads();
    if (t < 128) {
      const int hh = t >> 6, oo2 = t & 63;
      const int base = hh * 8;
      float s = lds[oo2][base] + lds[oo2][base + 1] + lds[oo2][base + 2] + lds[oo2][base + 3];
      float s2 = lds[oo2][base + 4] + lds[oo2][base + 5] + lds[oo2][base + 6] + lds[oo2][base + 7];
      float* ps = pstats + (((size_t)blockIdx.z * 32 + blockIdx.x) * 256 +
                            (size_t)blockIdx.y * 128 + hh * 64 + oo2) * 2;
      ps[0] = s; ps[1] = s2;
    }
  }
}

// ---------------- fused NMF kernel (LDS-staged basesT + coef) ----------------
// MODE 0: coef = softmax(h^T bases)
// MODE 1: btb; coef *= num/(coef btb + eps); ctc,xc partials
// MODE 2: btb; coef update; rec_nd = coef @ bases^T
template<int MODE>
__global__ __launch_bounds__(512)
void nmf_kernel(const u16* __restrict__ h_nd, const u16* __restrict__ h_dn,
                const u16* __restrict__ basesT, const u16* __restrict__ bases_bf,
                u16* __restrict__ coef_bf, u16* __restrict__ rec_nd,
                float* __restrict__ ctcp, float* __restrict__ xcp) {
  const int nc0 = blockIdx.x * NCH_;
  const int b = blockIdx.y;
  const int t = threadIdx.x, w = t >> 6, lane = t & 63, g = lane >> 4, c = lane & 15;
  __shared__ u16 bT_s[64 * 256];       // 32KB swizzled basesT
  __shared__ u16 btb_s[64][72];
  __shared__ u16 coef_s[128][72];
  __shared__ u16 coefT_s[64][136];
  const u16* hb = h_nd + (size_t)b * N_ * C_;
  const u16* bT = basesT + (size_t)b * R_ * C_;
  u16* cb = coef_bf + (size_t)b * N_ * R_;

  // stage basesT with 16B-chunk XOR swizzle: chunk k of row r -> slot k^(r&7)
#pragma unroll
  for (int i = 0; i < 4; ++i) {
    const int lin = t + i * 512;
    const int r = lin >> 5, k = lin & 31;
    *(uint4*)&bT_s[r * 256 + ((k ^ (r & 7)) * 8)] =
        *(const uint4*)&bT[(size_t)r * C_ + k * 8];
  }
  if (MODE != 0) {  // stage coef chunk
    const int row = t >> 2, seg = (t & 3) * 16;
    const u16* src = cb + (size_t)(nc0 + row) * R_ + seg;
    *(uint4*)&coef_s[row][seg] = *(const uint4*)src;
    *(uint4*)&coef_s[row][seg + 8] = *(const uint4*)(src + 8);
  }
  __syncthreads();

  const int nl = w * 16 + c;

  // Phase A/B: num = h^T bases (+ btb on waves 0..3 when MODE!=0)
  f4v num[4] = {}, bt[4] = {};
  const u16* An = hb + (size_t)(nc0 + nl) * C_;
  for (int k0 = 0; k0 < C_; k0 += 32) {
    const int kc = (k0 >> 3) + g;
    bf8v bv[4];
#pragma unroll
    for (int nj = 0; nj < 4; ++nj)
      bv[nj] = *(const bf8v*)&bT_s[(nj * 16 + c) * 256 + ((kc ^ (c & 7)) * 8)];
    bf8v a = ldf(An + k0 + g * 8);
#pragma unroll
    for (int nj = 0; nj < 4; ++nj) num[nj] = MFMA(a, bv[nj], num[nj]);
    if (MODE != 0 && w < 4) {
      bf8v a2 = *(const bf8v*)&bT_s[(w * 16 + c) * 256 + ((kc ^ (c & 7)) * 8)];
#pragma unroll
      for (int nj = 0; nj < 4; ++nj) bt[nj] = MFMA(a2, bv[nj], bt[nj]);
    }
  }

  if (MODE == 0) {
#pragma unroll
    for (int rg = 0; rg < 4; ++rg) {
      float m = fmaxf(fmaxf(num[0][rg], num[1][rg]), fmaxf(num[2][rg], num[3][rg]));
#pragma unroll
      for (int off = 1; off < 16; off <<= 1) m = fmaxf(m, __shfl_xor(m, off));
      float e[4], s = 0.f;
#pragma unroll
      for (int nj = 0; nj < 4; ++nj) { e[nj] = __expf(num[nj][rg] - m); s += e[nj]; }
#pragma unroll
      for (int off = 1; off < 16; off <<= 1) s += __shfl_xor(s, off);
      const float inv = 1.f / s;
      const int n = nc0 + w * 16 + g * 4 + rg;
#pragma unroll
      for (int nj = 0; nj < 4; ++nj)
        cb[(size_t)n * R_ + nj * 16 + c] = bf(e[nj] * inv);
    }
    return;
  }

  if (w < 4) {
#pragma unroll
    for (int nj = 0; nj < 4; ++nj)
#pragma unroll
      for (int rg = 0; rg < 4; ++rg)
        btb_s[w * 16 + g * 4 + rg][nj * 16 + c] = bf(bt[nj][rg]);
  }
  __syncthreads();

  // Phase C: den = coef @ btb (all from LDS)
  f4v den[4] = {};
#pragma unroll
  for (int k0 = 0; k0 < R_; k0 += 32) {
    bf8v a = *(const bf8v*)&coef_s[nl][k0 + g * 8];
#pragma unroll
    for (int nj = 0; nj < 4; ++nj)
      den[nj] = MFMA(a, *(const bf8v*)&btb_s[nj * 16 + c][k0 + g * 8], den[nj]);
  }
  __syncthreads();   // all C reads done before in-place update

  // Phase D: multiplicative update in LDS
#pragma unroll
  for (int nj = 0; nj < 4; ++nj)
#pragma unroll
    for (int rg = 0; rg < 4; ++rg) {
      const int row = w * 16 + g * 4 + rg, r = nj * 16 + c;
      const float old = bf2f(coef_s[row][r]);
      const u16 nv = bf(old * num[nj][rg] / (den[nj][rg] + EPS_));
      coef_s[row][r] = nv;
      if (MODE == 1) coefT_s[r][row] = nv;
    }
  __syncthreads();

  // coef write-back
  {
    const int row = t >> 2, seg = (t & 3) * 16;
    u16* dst = cb + (size_t)(nc0 + row) * R_ + seg;
    *(uint4*)dst = *(const uint4*)&coef_s[row][seg];
    *(uint4*)(dst + 8) = *(const uint4*)&coef_s[row][seg + 8];
  }

  if (MODE == 1) {
    // xc partial: all waves, d rows w*32 + mi*16, K = 128 local n
    f4v xa[2][4] = {};
    const u16* hd = h_dn + (size_t)b * C_ * N_;
    for (int k0 = 0; k0 < NCH_; k0 += 32) {
      bf8v bv[4];
#pragma unroll
      for (int nj = 0; nj < 4; ++nj)
        bv[nj] = *(const bf8v*)&coefT_s[nj * 16 + c][k0 + g * 8];
#pragma unroll
      for (int mi = 0; mi < 2; ++mi) {
        bf8v a = ldf(hd + (size_t)(w * 32 + mi * 16 + c) * N_ + nc0 + k0 + g * 8);
#pragma unroll
        for (int nj = 0; nj < 4; ++nj) xa[mi][nj] = MFMA(a, bv[nj], xa[mi][nj]);
      }
    }
    float* xo = xcp + ((size_t)b * NSP_ + blockIdx.x) * (C_ * R_);
#pragma unroll
    for (int mi = 0; mi < 2; ++mi)
#pragma unroll
      for (int nj = 0; nj < 4; ++nj)
#pragma unroll
        for (int rg = 0; rg < 4; ++rg)
          xo[(size_t)(w * 32 + mi * 16 + g * 4 + rg) * R_ + nj * 16 + c] = xa[mi][nj][rg];
    // ctc partial: waves 0..3
    if (w < 4) {
      f4v ca[4] = {};
      for (int k0 = 0; k0 < NCH_; k0 += 32) {
        bf8v a = *(const bf8v*)&coefT_s[w * 16 + c][k0 + g * 8];
#pragma unroll
        for (int nj = 0; nj < 4; ++nj)
          ca[nj] = MFMA(a, *(const bf8v*)&coefT_s[nj * 16 + c][k0 + g * 8], ca[nj]);
      }
      float* co = ctcp + ((size_t)b * NSP_ + blockIdx.x) * (R_ * R_);
#pragma unroll
      for (int nj = 0; nj < 4; ++nj)
#pragma unroll
        for (int rg = 0; rg < 4; ++rg)
          co[(size_t)(w * 16 + g * 4 + rg) * R_ + nj * 16 + c] = ca[nj][rg];
    }
  }

  if (MODE == 2) {
    f4v ra[8][2] = {};
    const u16* Bb = bases_bf + (size_t)b * C_ * R_;
#pragma unroll
    for (int k0 = 0; k0 < R_; k0 += 32) {
      bf8v bv[2];
#pragma unroll
      for (int nj = 0; nj < 2; ++nj)
        bv[nj] = ldf(Bb + (size_t)(w * 32 + nj * 16 + c) * R_ + k0 + g * 8);
#pragma unroll
      for (int mi = 0; mi < 8; ++mi) {
        bf8v a = *(const bf8v*)&coef_s[mi * 16 + c][k0 + g * 8];
#pragma unroll
        for (int nj = 0; nj < 2; ++nj) ra[mi][nj] = MFMA(a, bv[nj], ra[mi][nj]);
      }
    }
    u16* ro = rec_nd + (size_t)b * N_ * C_;
#pragma unroll
    for (int mi = 0; mi < 8; ++mi)
#pragma unroll
      for (int nj = 0; nj < 2; ++nj)
#pragma unroll
        for (int rg = 0; rg < 4; ++rg)
          ro[(size_t)(nc0 + mi * 16 + g * 4 + rg) * C_ + w * 32 + nj * 16 + c] =
              bf(ra[mi][nj][rg]);
  }
}

// ---------------- bases *= (x coef) / (bases ctc + eps); grid (16,8)x256 ----------
__global__ __launch_bounds__(256)
void bases_update_kernel(const float* __restrict__ xcp, const float* __restrict__ ctcp,
                         float* __restrict__ bases, u16* __restrict__ bases_bf,
                         u16* __restrict__ basesT) {
  const int dt = blockIdx.x & 3, rt = blockIdx.x >> 2, b = blockIdx.y;
  const int d0 = dt * 64, rb = rt * 16;
  float* bb = bases + (size_t)b * C_ * R_;
  __shared__ float ctc_s[64][16];
  __shared__ float b_s[64][65];
  const int t = threadIdx.x;
  {
    const int k = t >> 2, cr = (t & 3) * 4;
    float4 a = make_float4(0, 0, 0, 0);
    for (int s = 0; s < NSP_; ++s) {
      float4 v = *(const float4*)&ctcp[((size_t)b * NSP_ + s) * (R_ * R_) + (size_t)k * R_ + rb + cr];
      a.x += v.x; a.y += v.y; a.z += v.z; a.w += v.w;
    }
    *(float4*)&ctc_s[k][cr] = a;
  }
  {
    const int lc = t & 63, lr = t >> 6;
#pragma unroll
    for (int p = 0; p < 16; ++p)
      b_s[lr + 4 * p][lc] = bb[(size_t)(d0 + lr + 4 * p) * R_ + lc];
  }
  __syncthreads();
  const int dd = t >> 2, r0 = rb + (t & 3) * 4, cr = (t & 3) * 4;
  float4 num2 = make_float4(0, 0, 0, 0);
  for (int s = 0; s < NSP_; ++s) {
    float4 v = *(const float4*)&xcp[(((size_t)b * NSP_ + s) * C_ + d0 + dd) * R_ + r0];
    num2.x += v.x; num2.y += v.y; num2.z += v.z; num2.w += v.w;
  }
  float4 den = make_float4(0, 0, 0, 0);
#pragma unroll
  for (int k = 0; k < 64; ++k) {
    const float a = b_s[dd][k];
    float4 cv = *(const float4*)&ctc_s[k][cr];
    den.x = fmaf(a, cv.x, den.x); den.y = fmaf(a, cv.y, den.y);
    den.z = fmaf(a, cv.z, den.z); den.w = fmaf(a, cv.w, den.w);
  }
  float4 o;
  o.x = b_s[dd][r0 + 0] * num2.x / (den.x + EPS_);
  o.y = b_s[dd][r0 + 1] * num2.y / (den.y + EPS_);
  o.z = b_s[dd][r0 + 2] * num2.z / (den.z + EPS_);
  o.w = b_s[dd][r0 + 3] * num2.w / (den.w + EPS_);
  *(float4*)&bb[(size_t)(d0 + dd) * R_ + r0] = o;
  u16* obf = bases_bf + (size_t)b * C_ * R_ + (size_t)(d0 + dd) * R_ + r0;
  obf[0] = bf(o.x); obf[1] = bf(o.y); obf[2] = bf(o.z); obf[3] = bf(o.w);
  u16* oT = basesT + (size_t)b * R_ * C_ + d0 + dd;
  oT[(size_t)(r0 + 0) * C_] = bf(o.x); oT[(size_t)(r0 + 1) * C_] = bf(o.y);
  oT[(size_t)(r0 + 2) * C_] = bf(o.z); oT[(size_t)(r0 + 3) * C_] = bf(o.w);
}

// ---------------- GN reduce + affine + residual + relu ----------------
__global__ __launch_bounds__(256)
void gn_final_kernel(const float* __restrict__ x, const float* __restrict__ gamma,
                     const float* __restrict__ beta, const float* __restrict__ pstats,
                     float* __restrict__ out) {
  const int t = threadIdx.x;
  const size_t gid0 = (size_t)blockIdx.x * 256;
  const size_t idx0 = gid0 * 4;
  const int b = (int)(idx0 >> 20);
  const int c = (int)((idx0 & ((1u << 20) - 1)) >> 12);
  const int g = c >> 3;
  // reduce this (b,g)'s partial stats: 32 nb x 8 ch x 2
  float s, s2;
  {
    const int nb = t >> 3, ch = g * 8 + (t & 7);
    const float* ps = pstats + (((size_t)b * 32 + nb) * 256 + ch) * 2;
    s = ps[0]; s2 = ps[1];
  }
#pragma unroll
  for (int off = 32; off > 0; off >>= 1) { s += __shfl_down(s, off); s2 += __shfl_down(s2, off); }
  __shared__ float rs[4], rs2[4], fin[2];
  if ((t & 63) == 0) { rs[t >> 6] = s; rs2[t >> 6] = s2; }
  __syncthreads();
  if (t == 0) {
    float S = rs[0] + rs[1] + rs[2] + rs[3];
    float S2 = rs2[0] + rs2[1] + rs2[2] + rs2[3];
    float mean = S / 32768.f;
    float var = S2 / 32768.f - mean * mean;
    fin[0] = mean; fin[1] = rsqrtf(var + 1e-5f);
  }
  __syncthreads();
  const float mean = fin[0], rstd = fin[1];
  const float ga = gamma[c] * rstd;
  const float be = beta[c] - mean * ga;
  const size_t gid = gid0 + t;
  float4 ov = ((const float4*)out)[gid];
  float4 xv = ((const float4*)x)[gid];
  float4 r;
  r.x = fmaxf(fmaf(ov.x, ga, be) + xv.x, 0.f);
  r.y = fmaxf(fmaf(ov.y, ga, be) + xv.y, 0.f);
  r.z = fmaxf(fmaf(ov.z, ga, be) + xv.z, 0.f);
  r.w = fmaxf(fmaf(ov.w, ga, be) + xv.w, 0.f);
  ((float4*)out)[gid] = r;
}

extern "C" void kernel_launch(void* const* d_in, const int* in_sizes, int n_in,
                              void* d_out, int out_size, void* d_ws, size_t ws_size,
                              hipStream_t stream) {
  (void)in_sizes; (void)n_in; (void)out_size; (void)ws_size;
  const float* x     = (const float*)d_in[0];
  const float* w_in  = (const float*)d_in[1];
  const float* b_in  = (const float*)d_in[2];
  const float* w_out = (const float*)d_in[3];
  const float* gamma = (const float*)d_in[4];
  const float* beta  = (const float*)d_in[5];
  const float* binit = (const float*)d_in[6];
  float* out = (float*)d_out;

  float* p = (float*)d_ws;
  u16* xT = (u16*)p;        p += 4194304;   // B*N*C bf16; reused as rec_nd
  u16* rec_nd = xT;
  u16* h_nd = (u16*)p;      p += 4194304;   // B*N*C bf16
  u16* h_dn = (u16*)p;      p += 4194304;   // B*C*N bf16
  u16* coef_bf = (u16*)p;   p += 1048576;   // B*N*R bf16
  float* bases = p;         p += 131072;    // B*C*R f32
  u16* bases_bf = (u16*)p;  p += 65536;
  u16* basesT = (u16*)p;    p += 65536;
  float* ctcp = p;          p += 1048576;   // B*NSP*R*R f32
  float* xcp = p;           p += 4194304;   // B*NSP*C*R f32
  u16* w1b = (u16*)p;       p += 32768;     // C*C bf16
  u16* w2b = (u16*)p;       p += 32768;     // C*C bf16
  float* pstats = p;        p += 131072;    // B*32*256*2 f32

  prep_kernel<<<dim3(264), 256, 0, stream>>>(binit, bases, bases_bf, basesT,
                                             w_in, w_out, w1b, w2b);
  xpose_kernel<<<dim3(64, 4, 8), 256, 0, stream>>>(x, xT);
  conv_mfma_kernel<true><<<dim3(32, 2, 8), 256, 0, stream>>>(xT, w1b, b_in, h_dn, h_nd,
                                                             nullptr, nullptr);
  nmf_kernel<0><<<dim3(32, 8), 512, 0, stream>>>(h_nd, h_dn, basesT, bases_bf, coef_bf,
                                                 nullptr, nullptr, nullptr);
  for (int it = 0; it < STEPS_; ++it) {
    nmf_kernel<1><<<dim3(32, 8), 512, 0, stream>>>(h_nd, h_dn, basesT, bases_bf, coef_bf,
                                                   nullptr, ctcp, xcp);
    bases_update_kernel<<<dim3(16, 8), 256, 0, stream>>>(xcp, ctcp, bases, bases_bf, basesT);
  }
  nmf_kernel<2><<<dim3(32, 8), 512, 0, stream>>>(h_nd, h_dn, basesT, bases_bf, coef_bf,
                                                 rec_nd, nullptr, nullptr);
  conv_mfma_kernel<false><<<dim3(32, 2, 8), 256, 0, stream>>>(rec_nd, w2b, nullptr,
                                                              nullptr, nullptr, out, pstats);
  gn_final_kernel<<<dim3((B_ * C_ * N_) / 4 / 256), 256, 0, stream>>>(x, gamma, beta,
                                                                      pstats, out);
}

// Round 8
// 271.979 us; speedup vs baseline: 4.0266x; 1.0575x over previous
//
#include <hip/hip_runtime.h>

#define B_ 8
#define C_ 256
#define N_ 4096
#define R_ 64
#define STEPS_ 7
#define NCH_ 128
#define NSP_ 32
#define EPS_ 1e-6f

typedef unsigned short u16;
typedef short bf8v __attribute__((ext_vector_type(8)));
typedef float f4v __attribute__((ext_vector_type(4)));

#define MFMA(a, b, c) __builtin_amdgcn_mfma_f32_16x16x32_bf16((a), (b), (c), 0, 0, 0)

__device__ __forceinline__ u16 bf(float x) {
  union { float f; unsigned u; } v; v.f = x;
  return (u16)((v.u + 0x7FFFu + ((v.u >> 16) & 1u)) >> 16);
}
__device__ __forceinline__ float bf2f(u16 x) {
  union { unsigned u; float f; } v; v.u = (unsigned)x << 16; return v.f;
}
__device__ __forceinline__ bf8v ldf(const u16* p) { return *(const bf8v*)p; }

// ---------------- prep: norm_bases (blocks 0..7) + weight cvt (blocks 8..263) ----
__global__ __launch_bounds__(256)
void prep_kernel(const float* __restrict__ binit, float* __restrict__ bases,
                 u16* __restrict__ basesT,
                 const float* __restrict__ w1, const float* __restrict__ w2,
                 u16* __restrict__ w1b, u16* __restrict__ w2b) {
  const int t = threadIdx.x;
  if (blockIdx.x >= 8) {
    const int i = (blockIdx.x - 8) * 256 + t;
    w1b[i] = bf(w1[i]);
    w2b[i] = bf(w2[i]);
    return;
  }
  const int b = blockIdx.x;
  const int rr = t & 63, dq = t >> 6;
  const float* src = binit + (size_t)b * C_ * R_;
  float* dst = bases + (size_t)b * C_ * R_;
  u16* dT  = basesT + (size_t)b * R_ * C_;
  float vals[64];
  float s = 0.f;
#pragma unroll
  for (int i = 0; i < 64; ++i) {
    float v = src[(size_t)(dq + 4 * i) * R_ + rr];
    vals[i] = v; s = fmaf(v, v, s);
  }
  __shared__ float red[4][64];
  red[dq][rr] = s;
  __syncthreads();
  float nrm = fmaxf(sqrtf(red[0][rr] + red[1][rr] + red[2][rr] + red[3][rr]), 1e-12f);
  const float inv = 1.f / nrm;
#pragma unroll
  for (int i = 0; i < 64; ++i) {
    const int d = dq + 4 * i;
    const float v = vals[i] * inv;
    dst[(size_t)d * R_ + rr] = v;
    dT[(size_t)rr * C_ + d]  = bf(v);
  }
}

// ---------------- x (b,c,n) f32 -> xT (b,n,c) bf16 ----------------
__global__ __launch_bounds__(256)
void xpose_kernel(const float* __restrict__ x, u16* __restrict__ xT) {
  const int n0 = blockIdx.x * 64, c0 = blockIdx.y * 64, b = blockIdx.z;
  __shared__ float lds[64][65];
  const int t = threadIdx.x;
  const float* xb = x + (size_t)b * C_ * N_;
  const int row = t >> 4, col4 = (t & 15) * 4;
#pragma unroll
  for (int p = 0; p < 4; ++p) {
    float4 v = *(const float4*)&xb[(size_t)(c0 + row + 16 * p) * N_ + n0 + col4];
    lds[row + 16 * p][col4 + 0] = v.x; lds[row + 16 * p][col4 + 1] = v.y;
    lds[row + 16 * p][col4 + 2] = v.z; lds[row + 16 * p][col4 + 3] = v.w;
  }
  __syncthreads();
  const int r = t >> 2, cb = (t & 3) * 16;
  __align__(16) u16 tmp[16];
#pragma unroll
  for (int j = 0; j < 16; ++j) tmp[j] = bf(lds[cb + j][r]);
  u16* o = xT + (size_t)b * N_ * C_ + (size_t)(n0 + r) * C_ + c0 + cb;
  *(uint4*)o = *(uint4*)tmp;
  *(uint4*)(o + 8) = *(uint4*)(tmp + 8);
}

// ---------------- conv1 via MFMA: 128x128 tile, +bias+relu, h_dn + h_nd ----------
__global__ __launch_bounds__(256)
void conv1_kernel(const u16* __restrict__ A, const u16* __restrict__ W,
                  const float* __restrict__ bias, u16* __restrict__ h_dn,
                  u16* __restrict__ h_nd) {
  const int nb0 = blockIdx.x * 128, ob0 = blockIdx.y * 128, b = blockIdx.z;
  const int t = threadIdx.x, w = t >> 6, lane = t & 63, g = lane >> 4, c = lane & 15;
  const int n_base = nb0 + (w >> 1) * 64, o_base = ob0 + (w & 1) * 64;
  const u16* Ab = A + (size_t)b * N_ * C_;
  f4v acc[4][4] = {};
  for (int k0 = 0; k0 < C_; k0 += 32) {
    bf8v av[4], wv[4];
#pragma unroll
    for (int mi = 0; mi < 4; ++mi)
      av[mi] = ldf(Ab + (size_t)(n_base + mi * 16 + c) * C_ + k0 + g * 8);
#pragma unroll
    for (int nj = 0; nj < 4; ++nj)
      wv[nj] = ldf(W + (size_t)(o_base + nj * 16 + c) * C_ + k0 + g * 8);
#pragma unroll
    for (int mi = 0; mi < 4; ++mi)
#pragma unroll
      for (int nj = 0; nj < 4; ++nj)
        acc[mi][nj] = MFMA(av[mi], wv[nj], acc[mi][nj]);
  }
  __shared__ float lds[64][65];
  for (int p = 0; p < 4; ++p) {
    if (w == p) {
#pragma unroll
      for (int mi = 0; mi < 4; ++mi)
#pragma unroll
        for (int nj = 0; nj < 4; ++nj) {
          const float bb = bias[o_base + nj * 16 + c];
#pragma unroll
          for (int rg = 0; rg < 4; ++rg)
            lds[mi * 16 + g * 4 + rg][nj * 16 + c] = fmaxf(acc[mi][nj][rg] + bb, 0.f);
        }
    }
    __syncthreads();
    const int pn = nb0 + (p >> 1) * 64, po = ob0 + (p & 1) * 64;
    {
      const int n = t >> 2, ob2 = (t & 3) * 16;
      __align__(16) u16 tmp[16];
#pragma unroll
      for (int j = 0; j < 16; ++j) tmp[j] = bf(lds[n][ob2 + j]);
      u16* o = h_nd + (size_t)b * N_ * C_ + (size_t)(pn + n) * C_ + po + ob2;
      *(uint4*)o = *(uint4*)tmp; *(uint4*)(o + 8) = *(uint4*)(tmp + 8);
    }
    {
      const int oo = t >> 2, nb2 = (t & 3) * 16;
      __align__(16) u16 tmp[16];
#pragma unroll
      for (int j = 0; j < 16; ++j) tmp[j] = bf(lds[nb2 + j][oo]);
      u16* o = h_dn + (size_t)b * C_ * N_ + (size_t)(po + oo) * N_ + pn + nb2;
      *(uint4*)o = *(uint4*)tmp; *(uint4*)(o + 8) = *(uint4*)(tmp + 8);
    }
    __syncthreads();
  }
}

// ---------------- fused NMF kernel ----------------
// MODE 0: coef = softmax(num) in LDS, then update + partials   (first iteration)
// MODE 1: stage coef, update + partials                        (mid iterations)
// MODE 2: stage coef, update only; block x==0 computes M2 = W2 @ bases (per b)
template<int MODE>
__global__ __launch_bounds__(512)
void nmf_kernel(const u16* __restrict__ h_nd, const u16* __restrict__ h_dn,
                const u16* __restrict__ basesT, const u16* __restrict__ w2b,
                u16* __restrict__ coef_bf, u16* __restrict__ m2_bf,
                float* __restrict__ ctcp, float* __restrict__ xcp) {
  const int nc0 = blockIdx.x * NCH_;
  const int b = blockIdx.y;
  const int t = threadIdx.x, w = t >> 6, lane = t & 63, g = lane >> 4, c = lane & 15;
  __shared__ u16 bT_s[64 * 256];       // 32KB swizzled basesT
  __shared__ u16 btb_s[64][72];
  __shared__ u16 coef_s[128][72];
  __shared__ u16 coefT_s[64][136];
  const u16* hb = h_nd + (size_t)b * N_ * C_;
  const u16* bT = basesT + (size_t)b * R_ * C_;
  u16* cb = coef_bf + (size_t)b * N_ * R_;

  // stage basesT with 16B-chunk XOR swizzle: chunk k of row r -> slot k^(r&7)
#pragma unroll
  for (int i = 0; i < 4; ++i) {
    const int lin = t + i * 512;
    const int r = lin >> 5, k = lin & 31;
    *(uint4*)&bT_s[r * 256 + ((k ^ (r & 7)) * 8)] =
        *(const uint4*)&bT[(size_t)r * C_ + k * 8];
  }
  if (MODE != 0) {  // stage coef chunk
    const int row = t >> 2, seg = (t & 3) * 16;
    const u16* src = cb + (size_t)(nc0 + row) * R_ + seg;
    *(uint4*)&coef_s[row][seg] = *(const uint4*)src;
    *(uint4*)&coef_s[row][seg + 8] = *(const uint4*)(src + 8);
  }
  __syncthreads();

  const int nl = w * 16 + c;

  // Phase A/B: num = h^T bases  (+ btb on waves 0..3)
  f4v num[4] = {}, bt[4] = {};
  const u16* An = hb + (size_t)(nc0 + nl) * C_;
  for (int k0 = 0; k0 < C_; k0 += 32) {
    const int kc = (k0 >> 3) + g;
    bf8v bv[4];
#pragma unroll
    for (int nj = 0; nj < 4; ++nj)
      bv[nj] = *(const bf8v*)&bT_s[(nj * 16 + c) * 256 + ((kc ^ (c & 7)) * 8)];
    bf8v a = ldf(An + k0 + g * 8);
#pragma unroll
    for (int nj = 0; nj < 4; ++nj) num[nj] = MFMA(a, bv[nj], num[nj]);
    if (w < 4) {
      bf8v a2 = *(const bf8v*)&bT_s[(w * 16 + c) * 256 + ((kc ^ (c & 7)) * 8)];
#pragma unroll
      for (int nj = 0; nj < 4; ++nj) bt[nj] = MFMA(a2, bv[nj], bt[nj]);
    }
  }

  if (MODE == 0) {
    // coef_init = softmax over r (INV_T = 1)
#pragma unroll
    for (int rg = 0; rg < 4; ++rg) {
      float m = fmaxf(fmaxf(num[0][rg], num[1][rg]), fmaxf(num[2][rg], num[3][rg]));
#pragma unroll
      for (int off = 1; off < 16; off <<= 1) m = fmaxf(m, __shfl_xor(m, off));
      float e[4], s = 0.f;
#pragma unroll
      for (int nj = 0; nj < 4; ++nj) { e[nj] = __expf(num[nj][rg] - m); s += e[nj]; }
#pragma unroll
      for (int off = 1; off < 16; off <<= 1) s += __shfl_xor(s, off);
      const float inv = 1.f / s;
#pragma unroll
      for (int nj = 0; nj < 4; ++nj)
        coef_s[w * 16 + g * 4 + rg][nj * 16 + c] = bf(e[nj] * inv);
    }
  }

  if (w < 4) {
#pragma unroll
    for (int nj = 0; nj < 4; ++nj)
#pragma unroll
      for (int rg = 0; rg < 4; ++rg)
        btb_s[w * 16 + g * 4 + rg][nj * 16 + c] = bf(bt[nj][rg]);
  }
  __syncthreads();

  // Phase C: den = coef @ btb (LDS)
  f4v den[4] = {};
#pragma unroll
  for (int k0 = 0; k0 < R_; k0 += 32) {
    bf8v a = *(const bf8v*)&coef_s[nl][k0 + g * 8];
#pragma unroll
    for (int nj = 0; nj < 4; ++nj)
      den[nj] = MFMA(a, *(const bf8v*)&btb_s[nj * 16 + c][k0 + g * 8], den[nj]);
  }
  __syncthreads();

  // Phase D: multiplicative update in LDS
#pragma unroll
  for (int nj = 0; nj < 4; ++nj)
#pragma unroll
    for (int rg = 0; rg < 4; ++rg) {
      const int row = w * 16 + g * 4 + rg, r = nj * 16 + c;
      const float old = bf2f(coef_s[row][r]);
      const u16 nv = bf(old * num[nj][rg] / (den[nj][rg] + EPS_));
      coef_s[row][r] = nv;
      if (MODE <= 1) coefT_s[r][row] = nv;
    }
  __syncthreads();

  // coef write-back
  {
    const int row = t >> 2, seg = (t & 3) * 16;
    u16* dst = cb + (size_t)(nc0 + row) * R_ + seg;
    *(uint4*)dst = *(const uint4*)&coef_s[row][seg];
    *(uint4*)(dst + 8) = *(const uint4*)&coef_s[row][seg + 8];
  }

  if (MODE <= 1) {
    // xc partial: all waves, d rows w*32 + mi*16, K = 128 local n
    f4v xa[2][4] = {};
    const u16* hd = h_dn + (size_t)b * C_ * N_;
    for (int k0 = 0; k0 < NCH_; k0 += 32) {
      bf8v bv[4];
#pragma unroll
      for (int nj = 0; nj < 4; ++nj)
        bv[nj] = *(const bf8v*)&coefT_s[nj * 16 + c][k0 + g * 8];
#pragma unroll
      for (int mi = 0; mi < 2; ++mi) {
        bf8v a = ldf(hd + (size_t)(w * 32 + mi * 16 + c) * N_ + nc0 + k0 + g * 8);
#pragma unroll
        for (int nj = 0; nj < 4; ++nj) xa[mi][nj] = MFMA(a, bv[nj], xa[mi][nj]);
      }
    }
    float* xo = xcp + ((size_t)b * NSP_ + blockIdx.x) * (C_ * R_);
#pragma unroll
    for (int mi = 0; mi < 2; ++mi)
#pragma unroll
      for (int nj = 0; nj < 4; ++nj)
#pragma unroll
        for (int rg = 0; rg < 4; ++rg)
          xo[(size_t)(w * 32 + mi * 16 + g * 4 + rg) * R_ + nj * 16 + c] = xa[mi][nj][rg];
    // ctc partial: waves 0..3
    if (w < 4) {
      f4v ca[4] = {};
      for (int k0 = 0; k0 < NCH_; k0 += 32) {
        bf8v a = *(const bf8v*)&coefT_s[w * 16 + c][k0 + g * 8];
#pragma unroll
        for (int nj = 0; nj < 4; ++nj)
          ca[nj] = MFMA(a, *(const bf8v*)&coefT_s[nj * 16 + c][k0 + g * 8], ca[nj]);
      }
      float* co = ctcp + ((size_t)b * NSP_ + blockIdx.x) * (R_ * R_);
#pragma unroll
      for (int nj = 0; nj < 4; ++nj)
#pragma unroll
        for (int rg = 0; rg < 4; ++rg)
          co[(size_t)(w * 16 + g * 4 + rg) * R_ + nj * 16 + c] = ca[nj][rg];
    }
  }

  if (MODE == 2 && blockIdx.x == 0) {
    // M2[o,r] = sum_d W2[o,d] * bases[d,r]; B-frags from staged swizzled basesT
    f4v ma[2][4] = {};
    for (int k0 = 0; k0 < C_; k0 += 32) {
      const int kc = (k0 >> 3) + g;
      bf8v bv[4];
#pragma unroll
      for (int nj = 0; nj < 4; ++nj)
        bv[nj] = *(const bf8v*)&bT_s[(nj * 16 + c) * 256 + ((kc ^ (c & 7)) * 8)];
#pragma unroll
      for (int mi = 0; mi < 2; ++mi) {
        bf8v a = ldf(w2b + (size_t)(w * 32 + mi * 16 + c) * C_ + k0 + g * 8);
#pragma unroll
        for (int nj = 0; nj < 4; ++nj) ma[mi][nj] = MFMA(a, bv[nj], ma[mi][nj]);
      }
    }
    u16* mo = m2_bf + (size_t)b * C_ * R_;
#pragma unroll
    for (int mi = 0; mi < 2; ++mi)
#pragma unroll
      for (int nj = 0; nj < 4; ++nj)
#pragma unroll
        for (int rg = 0; rg < 4; ++rg)
          mo[(size_t)(w * 32 + mi * 16 + g * 4 + rg) * R_ + nj * 16 + c] = bf(ma[mi][nj][rg]);
  }
}

// ---------------- bases *= (x coef) / (bases ctc + eps); grid (16,8)x256 ----------
__global__ __launch_bounds__(256)
void bases_update_kernel(const float* __restrict__ xcp, const float* __restrict__ ctcp,
                         float* __restrict__ bases, u16* __restrict__ basesT) {
  const int dt = blockIdx.x & 3, rt = blockIdx.x >> 2, b = blockIdx.y;
  const int d0 = dt * 64, rb = rt * 16;
  float* bb = bases + (size_t)b * C_ * R_;
  __shared__ float ctc_s[64][16];
  __shared__ float b_s[64][65];
  const int t = threadIdx.x;
  {
    const int k = t >> 2, cr = (t & 3) * 4;
    float4 a = make_float4(0, 0, 0, 0);
    for (int s = 0; s < NSP_; ++s) {
      float4 v = *(const float4*)&ctcp[((size_t)b * NSP_ + s) * (R_ * R_) + (size_t)k * R_ + rb + cr];
      a.x += v.x; a.y += v.y; a.z += v.z; a.w += v.w;
    }
    *(float4*)&ctc_s[k][cr] = a;
  }
  {
    const int lc = t & 63, lr = t >> 6;
#pragma unroll
    for (int p = 0; p < 16; ++p)
      b_s[lr + 4 * p][lc] = bb[(size_t)(d0 + lr + 4 * p) * R_ + lc];
  }
  __syncthreads();
  const int dd = t >> 2, r0 = rb + (t & 3) * 4, cr = (t & 3) * 4;
  float4 num2 = make_float4(0, 0, 0, 0);
  for (int s = 0; s < NSP_; ++s) {
    float4 v = *(const float4*)&xcp[(((size_t)b * NSP_ + s) * C_ + d0 + dd) * R_ + r0];
    num2.x += v.x; num2.y += v.y; num2.z += v.z; num2.w += v.w;
  }
  float4 den = make_float4(0, 0, 0, 0);
#pragma unroll
  for (int k = 0; k < 64; ++k) {
    const float a = b_s[dd][k];
    float4 cv = *(const float4*)&ctc_s[k][cr];
    den.x = fmaf(a, cv.x, den.x); den.y = fmaf(a, cv.y, den.y);
    den.z = fmaf(a, cv.z, den.z); den.w = fmaf(a, cv.w, den.w);
  }
  float4 o;
  o.x = b_s[dd][r0 + 0] * num2.x / (den.x + EPS_);
  o.y = b_s[dd][r0 + 1] * num2.y / (den.y + EPS_);
  o.z = b_s[dd][r0 + 2] * num2.z / (den.z + EPS_);
  o.w = b_s[dd][r0 + 3] * num2.w / (den.w + EPS_);
  *(float4*)&bb[(size_t)(d0 + dd) * R_ + r0] = o;
  u16* oT = basesT + (size_t)b * R_ * C_ + d0 + dd;
  oT[(size_t)(r0 + 0) * C_] = bf(o.x); oT[(size_t)(r0 + 1) * C_] = bf(o.y);
  oT[(size_t)(r0 + 2) * C_] = bf(o.z); oT[(size_t)(r0 + 3) * C_] = bf(o.w);
}

// ---------------- conv2 via MFMA: out[o,n] = sum_r M2[o,r]*coef[n,r], K=64 --------
// writes of32 (o,n) + GN partial stats
__global__ __launch_bounds__(256)
void conv2_kernel(const u16* __restrict__ coef, const u16* __restrict__ m2,
                  float* __restrict__ of32, float* __restrict__ pstats) {
  const int nb0 = blockIdx.x * 128, ob0 = blockIdx.y * 128, b = blockIdx.z;
  const int t = threadIdx.x, w = t >> 6, lane = t & 63, g = lane >> 4, c = lane & 15;
  const int n_base = nb0 + (w >> 1) * 64, o_base = ob0 + (w & 1) * 64;
  const u16* Ab = coef + (size_t)b * N_ * R_;
  const u16* Wb = m2 + (size_t)b * C_ * R_;
  f4v acc[4][4] = {};
#pragma unroll
  for (int k0 = 0; k0 < R_; k0 += 32) {
    bf8v av[4], wv[4];
#pragma unroll
    for (int mi = 0; mi < 4; ++mi)
      av[mi] = ldf(Ab + (size_t)(n_base + mi * 16 + c) * R_ + k0 + g * 8);
#pragma unroll
    for (int nj = 0; nj < 4; ++nj)
      wv[nj] = ldf(Wb + (size_t)(o_base + nj * 16 + c) * R_ + k0 + g * 8);
#pragma unroll
    for (int mi = 0; mi < 4; ++mi)
#pragma unroll
      for (int nj = 0; nj < 4; ++nj)
        acc[mi][nj] = MFMA(av[mi], wv[nj], acc[mi][nj]);
  }
  __shared__ float lds[64][65];
  float sacc0 = 0.f, sacc1 = 0.f, s2acc0 = 0.f, s2acc1 = 0.f;
  for (int p = 0; p < 4; ++p) {
    if (w == p) {
#pragma unroll
      for (int mi = 0; mi < 4; ++mi)
#pragma unroll
        for (int nj = 0; nj < 4; ++nj)
#pragma unroll
          for (int rg = 0; rg < 4; ++rg)
            lds[mi * 16 + g * 4 + rg][nj * 16 + c] = acc[mi][nj][rg];
    }
    __syncthreads();
    const int pn = nb0 + (p >> 1) * 64, po = ob0 + (p & 1) * 64;
    const int oo = t >> 2, nb2 = (t & 3) * 16;
    float* o = of32 + (size_t)b * C_ * N_ + (size_t)(po + oo) * N_ + pn + nb2;
    float ls = 0.f, ls2 = 0.f;
#pragma unroll
    for (int q = 0; q < 4; ++q) {
      float4 v = make_float4(lds[nb2 + q * 4 + 0][oo], lds[nb2 + q * 4 + 1][oo],
                             lds[nb2 + q * 4 + 2][oo], lds[nb2 + q * 4 + 3][oo]);
      *(float4*)&o[q * 4] = v;
      ls += v.x + v.y + v.z + v.w;
      ls2 = fmaf(v.x, v.x, ls2); ls2 = fmaf(v.y, v.y, ls2);
      ls2 = fmaf(v.z, v.z, ls2); ls2 = fmaf(v.w, v.w, ls2);
    }
    if ((p & 1) == 0) { sacc0 += ls; s2acc0 += ls2; }
    else              { sacc1 += ls; s2acc1 += ls2; }
    __syncthreads();
  }
  {
    const int oo = t >> 2, q4 = t & 3;
    lds[oo][q4] = sacc0;      lds[oo][4 + q4] = s2acc0;
    lds[oo][8 + q4] = sacc1;  lds[oo][12 + q4] = s2acc1;
    __syncthreads();
    if (t < 128) {
      const int hh = t >> 6, oo2 = t & 63;
      const int base = hh * 8;
      float s = lds[oo2][base] + lds[oo2][base + 1] + lds[oo2][base + 2] + lds[oo2][base + 3];
      float s2 = lds[oo2][base + 4] + lds[oo2][base + 5] + lds[oo2][base + 6] + lds[oo2][base + 7];
      float* ps = pstats + (((size_t)blockIdx.z * 32 + blockIdx.x) * 256 +
                            (size_t)blockIdx.y * 128 + hh * 64 + oo2) * 2;
      ps[0] = s; ps[1] = s2;
    }
  }
}

// ---------------- GN reduce + affine + residual + relu ----------------
__global__ __launch_bounds__(256)
void gn_final_kernel(const float* __restrict__ x, const float* __restrict__ gamma,
                     const float* __restrict__ beta, const float* __restrict__ pstats,
                     float* __restrict__ out) {
  const int t = threadIdx.x;
  const size_t gid0 = (size_t)blockIdx.x * 256;
  const size_t idx0 = gid0 * 4;
  const int b = (int)(idx0 >> 20);
  const int c = (int)((idx0 & ((1u << 20) - 1)) >> 12);
  const int g = c >> 3;
  float s, s2;
  {
    const int nb = t >> 3, ch = g * 8 + (t & 7);
    const float* ps = pstats + (((size_t)b * 32 + nb) * 256 + ch) * 2;
    s = ps[0]; s2 = ps[1];
  }
#pragma unroll
  for (int off = 32; off > 0; off >>= 1) { s += __shfl_down(s, off); s2 += __shfl_down(s2, off); }
  __shared__ float rs[4], rs2[4], fin[2];
  if ((t & 63) == 0) { rs[t >> 6] = s; rs2[t >> 6] = s2; }
  __syncthreads();
  if (t == 0) {
    float S = rs[0] + rs[1] + rs[2] + rs[3];
    float S2 = rs2[0] + rs2[1] + rs2[2] + rs2[3];
    float mean = S / 32768.f;
    float var = S2 / 32768.f - mean * mean;
    fin[0] = mean; fin[1] = rsqrtf(var + 1e-5f);
  }
  __syncthreads();
  const float mean = fin[0], rstd = fin[1];
  const float ga = gamma[c] * rstd;
  const float be = beta[c] - mean * ga;
  const size_t gid = gid0 + t;
  float4 ov = ((const float4*)out)[gid];
  float4 xv = ((const float4*)x)[gid];
  float4 r;
  r.x = fmaxf(fmaf(ov.x, ga, be) + xv.x, 0.f);
  r.y = fmaxf(fmaf(ov.y, ga, be) + xv.y, 0.f);
  r.z = fmaxf(fmaf(ov.z, ga, be) + xv.z, 0.f);
  r.w = fmaxf(fmaf(ov.w, ga, be) + xv.w, 0.f);
  ((float4*)out)[gid] = r;
}

extern "C" void kernel_launch(void* const* d_in, const int* in_sizes, int n_in,
                              void* d_out, int out_size, void* d_ws, size_t ws_size,
                              hipStream_t stream) {
  (void)in_sizes; (void)n_in; (void)out_size; (void)ws_size;
  const float* x     = (const float*)d_in[0];
  const float* w_in  = (const float*)d_in[1];
  const float* b_in  = (const float*)d_in[2];
  const float* w_out = (const float*)d_in[3];
  const float* gamma = (const float*)d_in[4];
  const float* beta  = (const float*)d_in[5];
  const float* binit = (const float*)d_in[6];
  float* out = (float*)d_out;

  float* p = (float*)d_ws;
  u16* xT = (u16*)p;        p += 4194304;   // B*N*C bf16
  u16* h_nd = (u16*)p;      p += 4194304;   // B*N*C bf16
  u16* h_dn = (u16*)p;      p += 4194304;   // B*C*N bf16
  u16* coef_bf = (u16*)p;   p += 1048576;   // B*N*R bf16
  float* bases = p;         p += 131072;    // B*C*R f32
  u16* basesT = (u16*)p;    p += 65536;     // B*R*C bf16
  u16* m2_bf = (u16*)p;     p += 65536;     // B*C*R bf16
  float* ctcp = p;          p += 1048576;   // B*NSP*R*R f32
  float* xcp = p;           p += 4194304;   // B*NSP*C*R f32
  u16* w1b = (u16*)p;       p += 32768;     // C*C bf16
  u16* w2b = (u16*)p;       p += 32768;     // C*C bf16
  float* pstats = p;        p += 131072;    // B*32*256*2 f32

  prep_kernel<<<dim3(264), 256, 0, stream>>>(binit, bases, basesT, w_in, w_out, w1b, w2b);
  xpose_kernel<<<dim3(64, 4, 8), 256, 0, stream>>>(x, xT);
  conv1_kernel<<<dim3(32, 2, 8), 256, 0, stream>>>(xT, w1b, b_in, h_dn, h_nd);

  nmf_kernel<0><<<dim3(32, 8), 512, 0, stream>>>(h_nd, h_dn, basesT, w2b, coef_bf,
                                                 m2_bf, ctcp, xcp);
  bases_update_kernel<<<dim3(16, 8), 256, 0, stream>>>(xcp, ctcp, bases, basesT);
  for (int it = 1; it < STEPS_; ++it) {
    nmf_kernel<1><<<dim3(32, 8), 512, 0, stream>>>(h_nd, h_dn, basesT, w2b, coef_bf,
                                                   m2_bf, ctcp, xcp);
    bases_update_kernel<<<dim3(16, 8), 256, 0, stream>>>(xcp, ctcp, bases, basesT);
  }
  nmf_kernel<2><<<dim3(32, 8), 512, 0, stream>>>(h_nd, h_dn, basesT, w2b, coef_bf,
                                                 m2_bf, ctcp, xcp);
  conv2_kernel<<<dim3(32, 2, 8), 256, 0, stream>>>(coef_bf, m2_bf, out, pstats);
  gn_final_kernel<<<dim3((B_ * C_ * N_) / 4 / 256), 256, 0, stream>>>(x, gamma, beta,
                                                                      pstats, out);
}

// Round 9
// 253.543 us; speedup vs baseline: 4.3194x; 1.0727x over previous
//
#include <hip/hip_runtime.h>

#define B_ 8
#define C_ 256
#define N_ 4096
#define R_ 64
#define STEPS_ 7
#define NCH_ 128
#define NSP_ 32
#define EPS_ 1e-6f

typedef unsigned short u16;
typedef short bf8v __attribute__((ext_vector_type(8)));
typedef float f4v __attribute__((ext_vector_type(4)));

#define MFMA(a, b, c) __builtin_amdgcn_mfma_f32_16x16x32_bf16((a), (b), (c), 0, 0, 0)

__device__ __forceinline__ u16 bf(float x) {
  union { float f; unsigned u; } v; v.f = x;
  return (u16)((v.u + 0x7FFFu + ((v.u >> 16) & 1u)) >> 16);
}
__device__ __forceinline__ float bf2f(u16 x) {
  union { unsigned u; float f; } v; v.u = (unsigned)x << 16; return v.f;
}
__device__ __forceinline__ bf8v ldf(const u16* p) { return *(const bf8v*)p; }

// ---------------- prep: norm_bases (blocks 0..7) + weight cvt (blocks 8..263) ----
__global__ __launch_bounds__(256)
void prep_kernel(const float* __restrict__ binit, float* __restrict__ bases,
                 u16* __restrict__ basesT,
                 const float* __restrict__ w1, const float* __restrict__ w2,
                 u16* __restrict__ w1b, u16* __restrict__ w2b) {
  const int t = threadIdx.x;
  if (blockIdx.x >= 8) {
    const int i = (blockIdx.x - 8) * 256 + t;
    w1b[i] = bf(w1[i]);
    w2b[i] = bf(w2[i]);
    return;
  }
  const int b = blockIdx.x;
  const int rr = t & 63, dq = t >> 6;
  const float* src = binit + (size_t)b * C_ * R_;
  float* dst = bases + (size_t)b * C_ * R_;
  u16* dT  = basesT + (size_t)b * R_ * C_;
  float vals[64];
  float s = 0.f;
#pragma unroll
  for (int i = 0; i < 64; ++i) {
    float v = src[(size_t)(dq + 4 * i) * R_ + rr];
    vals[i] = v; s = fmaf(v, v, s);
  }
  __shared__ float red[4][64];
  red[dq][rr] = s;
  __syncthreads();
  float nrm = fmaxf(sqrtf(red[0][rr] + red[1][rr] + red[2][rr] + red[3][rr]), 1e-12f);
  const float inv = 1.f / nrm;
#pragma unroll
  for (int i = 0; i < 64; ++i) {
    const int d = dq + 4 * i;
    const float v = vals[i] * inv;
    dst[(size_t)d * R_ + rr] = v;
    dT[(size_t)rr * C_ + d]  = bf(v);
  }
}

// ---------------- conv1 via MFMA, fused x transpose: reads x f32 (c,n) directly ----
// 128x128 tile, 64x64 per wave; +bias+relu; writes h_dn (d,n) + h_nd (n,d) bf16
__global__ __launch_bounds__(256)
void conv1_kernel(const float* __restrict__ x, const u16* __restrict__ W,
                  const float* __restrict__ bias, u16* __restrict__ h_dn,
                  u16* __restrict__ h_nd) {
  const int nb0 = blockIdx.x * 128, ob0 = blockIdx.y * 128, b = blockIdx.z;
  const int t = threadIdx.x, w = t >> 6, lane = t & 63, g = lane >> 4, c = lane & 15;
  const int nloc = (w >> 1) * 64, o_base = ob0 + (w & 1) * 64;
  const float* xb = x + (size_t)b * C_ * N_ + nb0;
  __shared__ u16 xa_s[128][40];        // bf16 transposed x tile [n][k], 16B-aligned rows
  __shared__ float lds[64][65];        // epilogue staging
  const int skk = t >> 3, sn = (t & 7) * 16;
  f4v acc[4][4] = {};
  for (int k0 = 0; k0 < C_; k0 += 32) {
    if (k0) __syncthreads();
    const float* src = &xb[(size_t)(k0 + skk) * N_ + sn];
    float4 v0 = *(const float4*)src;
    float4 v1 = *(const float4*)(src + 4);
    float4 v2 = *(const float4*)(src + 8);
    float4 v3 = *(const float4*)(src + 12);
    xa_s[sn + 0][skk] = bf(v0.x);  xa_s[sn + 1][skk] = bf(v0.y);
    xa_s[sn + 2][skk] = bf(v0.z);  xa_s[sn + 3][skk] = bf(v0.w);
    xa_s[sn + 4][skk] = bf(v1.x);  xa_s[sn + 5][skk] = bf(v1.y);
    xa_s[sn + 6][skk] = bf(v1.z);  xa_s[sn + 7][skk] = bf(v1.w);
    xa_s[sn + 8][skk] = bf(v2.x);  xa_s[sn + 9][skk] = bf(v2.y);
    xa_s[sn + 10][skk] = bf(v2.z); xa_s[sn + 11][skk] = bf(v2.w);
    xa_s[sn + 12][skk] = bf(v3.x); xa_s[sn + 13][skk] = bf(v3.y);
    xa_s[sn + 14][skk] = bf(v3.z); xa_s[sn + 15][skk] = bf(v3.w);
    __syncthreads();
    bf8v av[4], wv[4];
#pragma unroll
    for (int mi = 0; mi < 4; ++mi)
      av[mi] = *(const bf8v*)&xa_s[nloc + mi * 16 + c][g * 8];
#pragma unroll
    for (int nj = 0; nj < 4; ++nj)
      wv[nj] = ldf(W + (size_t)(o_base + nj * 16 + c) * C_ + k0 + g * 8);
#pragma unroll
    for (int mi = 0; mi < 4; ++mi)
#pragma unroll
      for (int nj = 0; nj < 4; ++nj)
        acc[mi][nj] = MFMA(av[mi], wv[nj], acc[mi][nj]);
  }
  __syncthreads();
  for (int p = 0; p < 4; ++p) {
    if (w == p) {
#pragma unroll
      for (int mi = 0; mi < 4; ++mi)
#pragma unroll
        for (int nj = 0; nj < 4; ++nj) {
          const float bb = bias[o_base + nj * 16 + c];
#pragma unroll
          for (int rg = 0; rg < 4; ++rg)
            lds[mi * 16 + g * 4 + rg][nj * 16 + c] = fmaxf(acc[mi][nj][rg] + bb, 0.f);
        }
    }
    __syncthreads();
    const int pn = nb0 + (p >> 1) * 64, po = ob0 + (p & 1) * 64;
    {
      const int n = t >> 2, ob2 = (t & 3) * 16;
      __align__(16) u16 tmp[16];
#pragma unroll
      for (int j = 0; j < 16; ++j) tmp[j] = bf(lds[n][ob2 + j]);
      u16* o = h_nd + (size_t)b * N_ * C_ + (size_t)(pn + n) * C_ + po + ob2;
      *(uint4*)o = *(uint4*)tmp; *(uint4*)(o + 8) = *(uint4*)(tmp + 8);
    }
    {
      const int oo = t >> 2, nb2 = (t & 3) * 16;
      __align__(16) u16 tmp[16];
#pragma unroll
      for (int j = 0; j < 16; ++j) tmp[j] = bf(lds[nb2 + j][oo]);
      u16* o = h_dn + (size_t)b * C_ * N_ + (size_t)(po + oo) * N_ + pn + nb2;
      *(uint4*)o = *(uint4*)tmp; *(uint4*)(o + 8) = *(uint4*)(tmp + 8);
    }
    __syncthreads();
  }
}

// ---------------- fused NMF kernel ----------------
// MODE 0: coef = softmax(num) in LDS, then update + partials   (first iteration)
// MODE 1: stage coef, update + partials                        (mid iterations)
// MODE 2: stage coef, update only; block x==0 computes M2 = W2 @ bases (per b)
template<int MODE>
__global__ __launch_bounds__(512)
void nmf_kernel(const u16* __restrict__ h_nd, const u16* __restrict__ h_dn,
                const u16* __restrict__ basesT, const u16* __restrict__ w2b,
                u16* __restrict__ coef_bf, u16* __restrict__ m2_bf,
                float* __restrict__ ctcp, u16* __restrict__ xcp) {
  const int nc0 = blockIdx.x * NCH_;
  const int b = blockIdx.y;
  const int t = threadIdx.x, w = t >> 6, lane = t & 63, g = lane >> 4, c = lane & 15;
  __shared__ u16 bT_s[64 * 256];       // 32KB swizzled basesT
  __shared__ u16 btb_s[64][72];
  __shared__ u16 coef_s[128][72];
  __shared__ u16 coefT_s[64][136];
  const u16* hb = h_nd + (size_t)b * N_ * C_;
  const u16* bT = basesT + (size_t)b * R_ * C_;
  u16* cb = coef_bf + (size_t)b * N_ * R_;

  // stage basesT with 16B-chunk XOR swizzle: chunk k of row r -> slot k^(r&7)
#pragma unroll
  for (int i = 0; i < 4; ++i) {
    const int lin = t + i * 512;
    const int r = lin >> 5, k = lin & 31;
    *(uint4*)&bT_s[r * 256 + ((k ^ (r & 7)) * 8)] =
        *(const uint4*)&bT[(size_t)r * C_ + k * 8];
  }
  if (MODE != 0) {  // stage coef chunk
    const int row = t >> 2, seg = (t & 3) * 16;
    const u16* src = cb + (size_t)(nc0 + row) * R_ + seg;
    *(uint4*)&coef_s[row][seg] = *(const uint4*)src;
    *(uint4*)&coef_s[row][seg + 8] = *(const uint4*)(src + 8);
  }
  __syncthreads();

  const int nl = w * 16 + c;

  // Phase A/B: num = h^T bases  (+ btb on waves 0..3)
  f4v num[4] = {}, bt[4] = {};
  const u16* An = hb + (size_t)(nc0 + nl) * C_;
  for (int k0 = 0; k0 < C_; k0 += 32) {
    const int kc = (k0 >> 3) + g;
    bf8v bv[4];
#pragma unroll
    for (int nj = 0; nj < 4; ++nj)
      bv[nj] = *(const bf8v*)&bT_s[(nj * 16 + c) * 256 + ((kc ^ (c & 7)) * 8)];
    bf8v a = ldf(An + k0 + g * 8);
#pragma unroll
    for (int nj = 0; nj < 4; ++nj) num[nj] = MFMA(a, bv[nj], num[nj]);
    if (w < 4) {
      bf8v a2 = *(const bf8v*)&bT_s[(w * 16 + c) * 256 + ((kc ^ (c & 7)) * 8)];
#pragma unroll
      for (int nj = 0; nj < 4; ++nj) bt[nj] = MFMA(a2, bv[nj], bt[nj]);
    }
  }

  if (MODE == 0) {
    // coef_init = softmax over r (INV_T = 1)
#pragma unroll
    for (int rg = 0; rg < 4; ++rg) {
      float m = fmaxf(fmaxf(num[0][rg], num[1][rg]), fmaxf(num[2][rg], num[3][rg]));
#pragma unroll
      for (int off = 1; off < 16; off <<= 1) m = fmaxf(m, __shfl_xor(m, off));
      float e[4], s = 0.f;
#pragma unroll
      for (int nj = 0; nj < 4; ++nj) { e[nj] = __expf(num[nj][rg] - m); s += e[nj]; }
#pragma unroll
      for (int off = 1; off < 16; off <<= 1) s += __shfl_xor(s, off);
      const float inv = 1.f / s;
#pragma unroll
      for (int nj = 0; nj < 4; ++nj)
        coef_s[w * 16 + g * 4 + rg][nj * 16 + c] = bf(e[nj] * inv);
    }
  }

  if (w < 4) {
#pragma unroll
    for (int nj = 0; nj < 4; ++nj)
#pragma unroll
      for (int rg = 0; rg < 4; ++rg)
        btb_s[w * 16 + g * 4 + rg][nj * 16 + c] = bf(bt[nj][rg]);
  }
  __syncthreads();

  // Phase C: den = coef @ btb (LDS)
  f4v den[4] = {};
#pragma unroll
  for (int k0 = 0; k0 < R_; k0 += 32) {
    bf8v a = *(const bf8v*)&coef_s[nl][k0 + g * 8];
#pragma unroll
    for (int nj = 0; nj < 4; ++nj)
      den[nj] = MFMA(a, *(const bf8v*)&btb_s[nj * 16 + c][k0 + g * 8], den[nj]);
  }
  __syncthreads();

  // Phase D: multiplicative update in LDS
#pragma unroll
  for (int nj = 0; nj < 4; ++nj)
#pragma unroll
    for (int rg = 0; rg < 4; ++rg) {
      const int row = w * 16 + g * 4 + rg, r = nj * 16 + c;
      const float old = bf2f(coef_s[row][r]);
      const u16 nv = bf(old * num[nj][rg] / (den[nj][rg] + EPS_));
      coef_s[row][r] = nv;
      if (MODE <= 1) coefT_s[r][row] = nv;
    }
  __syncthreads();

  // coef write-back
  {
    const int row = t >> 2, seg = (t & 3) * 16;
    u16* dst = cb + (size_t)(nc0 + row) * R_ + seg;
    *(uint4*)dst = *(const uint4*)&coef_s[row][seg];
    *(uint4*)(dst + 8) = *(const uint4*)&coef_s[row][seg + 8];
  }

  if (MODE <= 1) {
    // xc partial: all waves, d rows w*32 + mi*16, K = 128 local n; bf16 out
    f4v xa[2][4] = {};
    const u16* hd = h_dn + (size_t)b * C_ * N_;
    for (int k0 = 0; k0 < NCH_; k0 += 32) {
      bf8v bv[4];
#pragma unroll
      for (int nj = 0; nj < 4; ++nj)
        bv[nj] = *(const bf8v*)&coefT_s[nj * 16 + c][k0 + g * 8];
#pragma unroll
      for (int mi = 0; mi < 2; ++mi) {
        bf8v a = ldf(hd + (size_t)(w * 32 + mi * 16 + c) * N_ + nc0 + k0 + g * 8);
#pragma unroll
        for (int nj = 0; nj < 4; ++nj) xa[mi][nj] = MFMA(a, bv[nj], xa[mi][nj]);
      }
    }
    u16* xo = xcp + ((size_t)b * NSP_ + blockIdx.x) * (C_ * R_);
#pragma unroll
    for (int mi = 0; mi < 2; ++mi)
#pragma unroll
      for (int nj = 0; nj < 4; ++nj)
#pragma unroll
        for (int rg = 0; rg < 4; ++rg)
          xo[(size_t)(w * 32 + mi * 16 + g * 4 + rg) * R_ + nj * 16 + c] = bf(xa[mi][nj][rg]);
    // ctc partial: waves 0..3 (f32)
    if (w < 4) {
      f4v ca[4] = {};
      for (int k0 = 0; k0 < NCH_; k0 += 32) {
        bf8v a = *(const bf8v*)&coefT_s[w * 16 + c][k0 + g * 8];
#pragma unroll
        for (int nj = 0; nj < 4; ++nj)
          ca[nj] = MFMA(a, *(const bf8v*)&coefT_s[nj * 16 + c][k0 + g * 8], ca[nj]);
      }
      float* co = ctcp + ((size_t)b * NSP_ + blockIdx.x) * (R_ * R_);
#pragma unroll
      for (int nj = 0; nj < 4; ++nj)
#pragma unroll
        for (int rg = 0; rg < 4; ++rg)
          co[(size_t)(w * 16 + g * 4 + rg) * R_ + nj * 16 + c] = ca[nj][rg];
    }
  }

  if (MODE == 2 && blockIdx.x == 0) {
    // M2[o,r] = sum_d W2[o,d] * bases[d,r]
    f4v ma[2][4] = {};
    for (int k0 = 0; k0 < C_; k0 += 32) {
      const int kc = (k0 >> 3) + g;
      bf8v bv[4];
#pragma unroll
      for (int nj = 0; nj < 4; ++nj)
        bv[nj] = *(const bf8v*)&bT_s[(nj * 16 + c) * 256 + ((kc ^ (c & 7)) * 8)];
#pragma unroll
      for (int mi = 0; mi < 2; ++mi) {
        bf8v a = ldf(w2b + (size_t)(w * 32 + mi * 16 + c) * C_ + k0 + g * 8);
#pragma unroll
        for (int nj = 0; nj < 4; ++nj) ma[mi][nj] = MFMA(a, bv[nj], ma[mi][nj]);
      }
    }
    u16* mo = m2_bf + (size_t)b * C_ * R_;
#pragma unroll
    for (int mi = 0; mi < 2; ++mi)
#pragma unroll
      for (int nj = 0; nj < 4; ++nj)
#pragma unroll
        for (int rg = 0; rg < 4; ++rg)
          mo[(size_t)(w * 32 + mi * 16 + g * 4 + rg) * R_ + nj * 16 + c] = bf(ma[mi][nj][rg]);
  }
}

// ---------------- bases *= (x coef) / (bases ctc + eps); grid (16,8)x256 ----------
__global__ __launch_bounds__(256)
void bases_update_kernel(const u16* __restrict__ xcp, const float* __restrict__ ctcp,
                         float* __restrict__ bases, u16* __restrict__ basesT) {
  const int dt = blockIdx.x & 3, rt = blockIdx.x >> 2, b = blockIdx.y;
  const int d0 = dt * 64, rb = rt * 16;
  float* bb = bases + (size_t)b * C_ * R_;
  __shared__ float ctc_s[64][16];
  __shared__ float b_s[64][65];
  const int t = threadIdx.x;
  {
    const int k = t >> 2, cr = (t & 3) * 4;
    float4 a = make_float4(0, 0, 0, 0);
    for (int s = 0; s < NSP_; ++s) {
      float4 v = *(const float4*)&ctcp[((size_t)b * NSP_ + s) * (R_ * R_) + (size_t)k * R_ + rb + cr];
      a.x += v.x; a.y += v.y; a.z += v.z; a.w += v.w;
    }
    *(float4*)&ctc_s[k][cr] = a;
  }
  {
    const int lc = t & 63, lr = t >> 6;
#pragma unroll
    for (int p = 0; p < 16; ++p)
      b_s[lr + 4 * p][lc] = bb[(size_t)(d0 + lr + 4 * p) * R_ + lc];
  }
  __syncthreads();
  const int dd = t >> 2, r0 = rb + (t & 3) * 4, cr = (t & 3) * 4;
  float4 num2 = make_float4(0, 0, 0, 0);
  for (int s = 0; s < NSP_; ++s) {
    ushort4 v = *(const ushort4*)&xcp[(((size_t)b * NSP_ + s) * C_ + d0 + dd) * R_ + r0];
    num2.x += bf2f(v.x); num2.y += bf2f(v.y);
    num2.z += bf2f(v.z); num2.w += bf2f(v.w);
  }
  float4 den = make_float4(0, 0, 0, 0);
#pragma unroll
  for (int k = 0; k < 64; ++k) {
    const float a = b_s[dd][k];
    float4 cv = *(const float4*)&ctc_s[k][cr];
    den.x = fmaf(a, cv.x, den.x); den.y = fmaf(a, cv.y, den.y);
    den.z = fmaf(a, cv.z, den.z); den.w = fmaf(a, cv.w, den.w);
  }
  float4 o;
  o.x = b_s[dd][r0 + 0] * num2.x / (den.x + EPS_);
  o.y = b_s[dd][r0 + 1] * num2.y / (den.y + EPS_);
  o.z = b_s[dd][r0 + 2] * num2.z / (den.z + EPS_);
  o.w = b_s[dd][r0 + 3] * num2.w / (den.w + EPS_);
  *(float4*)&bb[(size_t)(d0 + dd) * R_ + r0] = o;
  u16* oT = basesT + (size_t)b * R_ * C_ + d0 + dd;
  oT[(size_t)(r0 + 0) * C_] = bf(o.x); oT[(size_t)(r0 + 1) * C_] = bf(o.y);
  oT[(size_t)(r0 + 2) * C_] = bf(o.z); oT[(size_t)(r0 + 3) * C_] = bf(o.w);
}

// ---------------- conv2 via MFMA: out[o,n] = sum_r M2[o,r]*coef[n,r], K=64 --------
// writes of32 (o,n) + GN partial stats
__global__ __launch_bounds__(256)
void conv2_kernel(const u16* __restrict__ coef, const u16* __restrict__ m2,
                  float* __restrict__ of32, float* __restrict__ pstats) {
  const int nb0 = blockIdx.x * 128, ob0 = blockIdx.y * 128, b = blockIdx.z;
  const int t = threadIdx.x, w = t >> 6, lane = t & 63, g = lane >> 4, c = lane & 15;
  const int n_base = nb0 + (w >> 1) * 64, o_base = ob0 + (w & 1) * 64;
  const u16* Ab = coef + (size_t)b * N_ * R_;
  const u16* Wb = m2 + (size_t)b * C_ * R_;
  f4v acc[4][4] = {};
#pragma unroll
  for (int k0 = 0; k0 < R_; k0 += 32) {
    bf8v av[4], wv[4];
#pragma unroll
    for (int mi = 0; mi < 4; ++mi)
      av[mi] = ldf(Ab + (size_t)(n_base + mi * 16 + c) * R_ + k0 + g * 8);
#pragma unroll
    for (int nj = 0; nj < 4; ++nj)
      wv[nj] = ldf(Wb + (size_t)(o_base + nj * 16 + c) * R_ + k0 + g * 8);
#pragma unroll
    for (int mi = 0; mi < 4; ++mi)
#pragma unroll
      for (int nj = 0; nj < 4; ++nj)
        acc[mi][nj] = MFMA(av[mi], wv[nj], acc[mi][nj]);
  }
  __shared__ float lds[64][65];
  float sacc0 = 0.f, sacc1 = 0.f, s2acc0 = 0.f, s2acc1 = 0.f;
  for (int p = 0; p < 4; ++p) {
    if (w == p) {
#pragma unroll
      for (int mi = 0; mi < 4; ++mi)
#pragma unroll
        for (int nj = 0; nj < 4; ++nj)
#pragma unroll
          for (int rg = 0; rg < 4; ++rg)
            lds[mi * 16 + g * 4 + rg][nj * 16 + c] = acc[mi][nj][rg];
    }
    __syncthreads();
    const int pn = nb0 + (p >> 1) * 64, po = ob0 + (p & 1) * 64;
    const int oo = t >> 2, nb2 = (t & 3) * 16;
    float* o = of32 + (size_t)b * C_ * N_ + (size_t)(po + oo) * N_ + pn + nb2;
    float ls = 0.f, ls2 = 0.f;
#pragma unroll
    for (int q = 0; q < 4; ++q) {
      float4 v = make_float4(lds[nb2 + q * 4 + 0][oo], lds[nb2 + q * 4 + 1][oo],
                             lds[nb2 + q * 4 + 2][oo], lds[nb2 + q * 4 + 3][oo]);
      *(float4*)&o[q * 4] = v;
      ls += v.x + v.y + v.z + v.w;
      ls2 = fmaf(v.x, v.x, ls2); ls2 = fmaf(v.y, v.y, ls2);
      ls2 = fmaf(v.z, v.z, ls2); ls2 = fmaf(v.w, v.w, ls2);
    }
    if ((p & 1) == 0) { sacc0 += ls; s2acc0 += ls2; }
    else              { sacc1 += ls; s2acc1 += ls2; }
    __syncthreads();
  }
  {
    const int oo = t >> 2, q4 = t & 3;
    lds[oo][q4] = sacc0;      lds[oo][4 + q4] = s2acc0;
    lds[oo][8 + q4] = sacc1;  lds[oo][12 + q4] = s2acc1;
    __syncthreads();
    if (t < 128) {
      const int hh = t >> 6, oo2 = t & 63;
      const int base = hh * 8;
      float s = lds[oo2][base] + lds[oo2][base + 1] + lds[oo2][base + 2] + lds[oo2][base + 3];
      float s2 = lds[oo2][base + 4] + lds[oo2][base + 5] + lds[oo2][base + 6] + lds[oo2][base + 7];
      float* ps = pstats + (((size_t)blockIdx.z * 32 + blockIdx.x) * 256 +
                            (size_t)blockIdx.y * 128 + hh * 64 + oo2) * 2;
      ps[0] = s; ps[1] = s2;
    }
  }
}

// ---------------- GN reduce + affine + residual + relu ----------------
__global__ __launch_bounds__(256)
void gn_final_kernel(const float* __restrict__ x, const float* __restrict__ gamma,
                     const float* __restrict__ beta, const float* __restrict__ pstats,
                     float* __restrict__ out) {
  const int t = threadIdx.x;
  const size_t gid0 = (size_t)blockIdx.x * 256;
  const size_t idx0 = gid0 * 4;
  const int b = (int)(idx0 >> 20);
  const int c = (int)((idx0 & ((1u << 20) - 1)) >> 12);
  const int g = c >> 3;
  float s, s2;
  {
    const int nb = t >> 3, ch = g * 8 + (t & 7);
    const float* ps = pstats + (((size_t)b * 32 + nb) * 256 + ch) * 2;
    s = ps[0]; s2 = ps[1];
  }
#pragma unroll
  for (int off = 32; off > 0; off >>= 1) { s += __shfl_down(s, off); s2 += __shfl_down(s2, off); }
  __shared__ float rs[4], rs2[4], fin[2];
  if ((t & 63) == 0) { rs[t >> 6] = s; rs2[t >> 6] = s2; }
  __syncthreads();
  if (t == 0) {
    float S = rs[0] + rs[1] + rs[2] + rs[3];
    float S2 = rs2[0] + rs2[1] + rs2[2] + rs2[3];
    float mean = S / 32768.f;
    float var = S2 / 32768.f - mean * mean;
    fin[0] = mean; fin[1] = rsqrtf(var + 1e-5f);
  }
  __syncthreads();
  const float mean = fin[0], rstd = fin[1];
  const float ga = gamma[c] * rstd;
  const float be = beta[c] - mean * ga;
  const size_t gid = gid0 + t;
  float4 ov = ((const float4*)out)[gid];
  float4 xv = ((const float4*)x)[gid];
  float4 r;
  r.x = fmaxf(fmaf(ov.x, ga, be) + xv.x, 0.f);
  r.y = fmaxf(fmaf(ov.y, ga, be) + xv.y, 0.f);
  r.z = fmaxf(fmaf(ov.z, ga, be) + xv.z, 0.f);
  r.w = fmaxf(fmaf(ov.w, ga, be) + xv.w, 0.f);
  ((float4*)out)[gid] = r;
}

extern "C" void kernel_launch(void* const* d_in, const int* in_sizes, int n_in,
                              void* d_out, int out_size, void* d_ws, size_t ws_size,
                              hipStream_t stream) {
  (void)in_sizes; (void)n_in; (void)out_size; (void)ws_size;
  const float* x     = (const float*)d_in[0];
  const float* w_in  = (const float*)d_in[1];
  const float* b_in  = (const float*)d_in[2];
  const float* w_out = (const float*)d_in[3];
  const float* gamma = (const float*)d_in[4];
  const float* beta  = (const float*)d_in[5];
  const float* binit = (const float*)d_in[6];
  float* out = (float*)d_out;

  float* p = (float*)d_ws;
  u16* h_nd = (u16*)p;      p += 4194304;   // B*N*C bf16
  u16* h_dn = (u16*)p;      p += 4194304;   // B*C*N bf16
  u16* coef_bf = (u16*)p;   p += 1048576;   // B*N*R bf16
  float* bases = p;         p += 131072;    // B*C*R f32
  u16* basesT = (u16*)p;    p += 65536;     // B*R*C bf16
  u16* m2_bf = (u16*)p;     p += 65536;     // B*C*R bf16
  float* ctcp = p;          p += 1048576;   // B*NSP*R*R f32
  u16* xcp = (u16*)p;       p += 2097152;   // B*NSP*C*R bf16
  u16* w1b = (u16*)p;       p += 32768;     // C*C bf16
  u16* w2b = (u16*)p;       p += 32768;     // C*C bf16
  float* pstats = p;        p += 131072;    // B*32*256*2 f32

  prep_kernel<<<dim3(264), 256, 0, stream>>>(binit, bases, basesT, w_in, w_out, w1b, w2b);
  conv1_kernel<<<dim3(32, 2, 8), 256, 0, stream>>>(x, w1b, b_in, h_dn, h_nd);

  nmf_kernel<0><<<dim3(32, 8), 512, 0, stream>>>(h_nd, h_dn, basesT, w2b, coef_bf,
                                                 m2_bf, ctcp, xcp);
  bases_update_kernel<<<dim3(16, 8), 256, 0, stream>>>(xcp, ctcp, bases, basesT);
  for (int it = 1; it < STEPS_; ++it) {
    nmf_kernel<1><<<dim3(32, 8), 512, 0, stream>>>(h_nd, h_dn, basesT, w2b, coef_bf,
                                                   m2_bf, ctcp, xcp);
    bases_update_kernel<<<dim3(16, 8), 256, 0, stream>>>(xcp, ctcp, bases, basesT);
  }
  nmf_kernel<2><<<dim3(32, 8), 512, 0, stream>>>(h_nd, h_dn, basesT, w2b, coef_bf,
                                                 m2_bf, ctcp, xcp);
  conv2_kernel<<<dim3(32, 2, 8), 256, 0, stream>>>(coef_bf, m2_bf, out, pstats);
  gn_final_kernel<<<dim3((B_ * C_ * N_) / 4 / 256), 256, 0, stream>>>(x, gamma, beta,
                                                                      pstats, out);
}